// Round 3
// baseline (2223.889 us; speedup 1.0000x reference)
//
#include <hip/hip_runtime.h>
#include <hip/hip_bf16.h>
#include <math.h>

#define B_   8
#define H_   320
#define W_   320
#define HW_  (320*320)

// ---------------------------------------------------------------------------
// Repack ALL conv weights in one dispatch:
// [co][ci][ky][kx] -> [ci*K*K + ky*K + kx][co], 8 segments.
// ---------------------------------------------------------------------------
__global__ void repack_all_k(const float* __restrict__ sf1, const float* __restrict__ sf2,
                             const float* __restrict__ sg1, const float* __restrict__ sg2,
                             const float* __restrict__ sg3, const float* __restrict__ so1,
                             const float* __restrict__ so2, const float* __restrict__ so3,
                             float* __restrict__ dst){
    const int cum[8]  = {9216, 9504, 35104, 41504, 43104, 44704, 49504, 63904};
    const int cout[8] = {32, 1, 32, 8, 8, 8, 24, 24};
    const int ckk[8]  = {288, 288, 800, 800, 200, 200, 200, 600};
    const int doff[8] = {0, 9216, 9504, 35104, 41504, 43104, 44704, 49504};
    int i = blockIdx.x*256 + threadIdx.x;
    if (i >= 63904) return;
    int s = 0;
    while (i >= cum[s]) ++s;
    const int base = s ? cum[s-1] : 0;
    const int il = i - base;
    const float* src = (s==0)?sf1:(s==1)?sf2:(s==2)?sg1:(s==3)?sg2:(s==4)?sg3:(s==5)?so1:(s==6)?so2:so3;
    const int co = il / ckk[s];
    const int t  = il - co*ckk[s];
    dst[doff[s] + t*cout[s] + co] = src[il];
}

// ---------------------------------------------------------------------------
// Deform epilogue (device): given this pixel's 24 oa3 values (+bias applied),
// sample fusion with deformable 3x3 + gaussian-affinity mask, return |.|
// ---------------------------------------------------------------------------
__device__ __forceinline__
float deform_px(const float* val, const float* __restrict__ fus_b,
                const float* __restrict__ gk_b, float inv_s, int y, int x){
    float aff[8]; float sa = 0.f;
    #pragma unroll
    for (int n=0;n<8;++n){
        float a = tanhf(val[16+n]) * inv_s + gk_b[n];
        aff[n] = a; sa += fabsf(a);
    }
    sa += 1e-5f;
    sa = fmaxf(sa, 1.f);
    const float isa = 1.f/sa;
    float ssum = 0.f;
    #pragma unroll
    for (int n=0;n<8;++n){ aff[n] *= isa; ssum += aff[n]; }
    const float aff_ref = 1.f - ssum;

    float o = 0.f;
    #pragma unroll
    for (int k=0;k<9;++k){
        float dy, dx, m;
        if (k == 4){ dy = 0.f; dx = 0.f; m = aff_ref; }
        else {
            const int n = (k < 4) ? k : k-1;
            dy = val[2*n];
            dx = val[2*n+1];
            m  = aff[n];
        }
        float yy = (float)(y + k/3 - 1) + dy;
        float xx = (float)(x + k%3 - 1) + dx;
        float y0f = floorf(yy), x0f = floorf(xx);
        int   y0 = (int)y0f,    x0i = (int)x0f;
        float wy1 = yy - y0f, wy0 = 1.f - wy1;
        float wx1 = xx - x0f, wx0 = 1.f - wx1;
        float v00 = (y0  >=0 && y0  <H_ && x0i  >=0 && x0i  <W_) ? fus_b[ y0   *W_ + x0i  ] : 0.f;
        float v01 = (y0  >=0 && y0  <H_ && x0i+1>=0 && x0i+1<W_) ? fus_b[ y0   *W_ + x0i+1] : 0.f;
        float v10 = (y0+1>=0 && y0+1<H_ && x0i  >=0 && x0i  <W_) ? fus_b[(y0+1)*W_ + x0i  ] : 0.f;
        float v11 = (y0+1>=0 && y0+1<H_ && x0i+1>=0 && x0i+1<W_) ? fus_b[(y0+1)*W_ + x0i+1] : 0.f;
        o += m * (wy0*(wx0*v00 + wx1*v01) + wy1*(wx0*v10 + wx1*v11));
    }
    return fabsf(o);
}

// ---------------------------------------------------------------------------
// Fused direct conv.
//   IN_BN:  compute scale/shift in-kernel from producer's (sum,sumsq) + gamma/
//           beta, apply y=relu(x*sc+sh) at LDS-load time (halo zeroed after).
//   OUT_STATS: epilogue per-channel (sum,sumsq) via wave shuffle + LDS + one
//           atomicAdd per block per channel.
//   OUT_MODE: 0 raw, 1 +bias, 2 tanh(x+bias), 3 deform epilogue (+bias).
// 32x8 px tile per block, 256 threads, CCH-channel LDS chunks.
// ---------------------------------------------------------------------------
template<int CIN, int COUT, int K, int CCH, bool IN_BN, bool OUT_STATS, int OUT_MODE>
__global__ __launch_bounds__(256)
void conv_k(const float* __restrict__ in,
            const float* __restrict__ bn_sum, const float* __restrict__ bn_sq,
            const float* __restrict__ gamma, const float* __restrict__ beta,
            const float* __restrict__ w, const float* __restrict__ bias,
            float* __restrict__ out,
            float* __restrict__ osum, float* __restrict__ osq,
            const float* __restrict__ fus, const float* __restrict__ gk,
            const float* __restrict__ aff_scale){
    constexpr int PAD = K/2;
    constexpr int LW  = 32 + K - 1;
    constexpr int LH  = 8 + K - 1;
    constexpr int PS  = LW*LH;
    __shared__ float lds[CCH*PS];
    __shared__ float sc_sh[2][CIN];
    __shared__ float red[OUT_STATS ? 8*COUT : 1];

    const int tid = threadIdx.x;
    const int b   = blockIdx.z;
    const int x0 = blockIdx.x*32, y0 = blockIdx.y*8;

    if (IN_BN){
        if (tid < CIN){
            const float invN = 1.f/(float)(B_*HW_);
            float mu  = bn_sum[tid]*invN;
            float var = bn_sq[tid]*invN - mu*mu;
            float s = gamma[tid] * rsqrtf(var + 1e-5f);
            sc_sh[0][tid] = s;
            sc_sh[1][tid] = beta[tid] - mu*s;
        }
        __syncthreads();
    }

    float acc[COUT];
    #pragma unroll
    for (int i=0;i<COUT;++i) acc[i] = 0.f;

    const int lane  = tid & 31;
    const int pslot = tid >> 5;
    const int tx = tid & 31, ty = tid >> 5;

    for (int c0=0; c0<CIN; c0+=CCH){
        if (c0) __syncthreads();
        // ---- stage CCH input planes (rows: add-only index math) ----
        #pragma unroll
        for (int pp=0; pp<CCH/8; ++pp){
            const int pl = pslot + pp*8;
            const int ci = c0 + pl;
            float sc = 1.f, sh = 0.f;
            if (IN_BN){ sc = sc_sh[0][ci]; sh = sc_sh[1][ci]; }
            const float* src = in + ((long)b*CIN + ci)*HW_;
            float* dst = lds + pl*PS;
            #pragma unroll
            for (int r=0; r<LH; ++r){
                const int gy = y0 + r - PAD;
                const bool rowok = (gy>=0) & (gy<H_);
                {
                    const int gx = x0 + lane - PAD;
                    float v = 0.f;
                    if (rowok && gx>=0 && gx<W_){
                        v = src[gy*W_ + gx];
                        if (IN_BN) v = fmaxf(fmaf(v, sc, sh), 0.f);
                    }
                    dst[r*LW + lane] = v;
                }
                if (lane < LW-32){
                    const int col = lane + 32;
                    const int gx = x0 + col - PAD;
                    float v = 0.f;
                    if (rowok && gx>=0 && gx<W_){
                        v = src[gy*W_ + gx];
                        if (IN_BN) v = fmaxf(fmaf(v, sc, sh), 0.f);
                    }
                    dst[r*LW + col] = v;
                }
            }
        }
        __syncthreads();
        // ---- compute ----
        for (int pl=0; pl<CCH; ++pl){
            const float* wb = w + (long)(c0+pl)*(K*K*COUT);
            const float* lp = lds + pl*PS + ty*LW + tx;
            #pragma unroll
            for (int ky=0; ky<K; ++ky){
                #pragma unroll
                for (int kx=0; kx<K; ++kx){
                    const float v = lp[ky*LW + kx];
                    const float* wt = wb + (ky*K+kx)*COUT;
                    #pragma unroll
                    for (int co=0; co<COUT; ++co)
                        acc[co] = fmaf(v, wt[co], acc[co]);
                }
            }
        }
    }

    // ---- fused BN-stats epilogue (on raw pre-bias acc) ----
    if (OUT_STATS){
        const int wid = tid >> 6, wl = tid & 63;
        #pragma unroll
        for (int co=0; co<COUT; ++co){
            float v = acc[co], v2 = v*v;
            #pragma unroll
            for (int off=32; off; off>>=1){
                v  += __shfl_down(v,  off, 64);
                v2 += __shfl_down(v2, off, 64);
            }
            if (wl == 0){
                red[(wid*COUT+co)*2  ] = v;
                red[(wid*COUT+co)*2+1] = v2;
            }
        }
        __syncthreads();
        if (tid < COUT){
            float s  = red[tid*2]          + red[(COUT+tid)*2]
                     + red[(2*COUT+tid)*2] + red[(3*COUT+tid)*2];
            float s2 = red[tid*2+1]          + red[(COUT+tid)*2+1]
                     + red[(2*COUT+tid)*2+1] + red[(3*COUT+tid)*2+1];
            atomicAdd(&osum[tid], s);
            atomicAdd(&osq[tid],  s2);
        }
    }

    const int gy = y0+ty, gx = x0+tx;
    if (OUT_MODE == 3){
        // oa3 + deform fused: acc[24]+bias are this px's oa3 channels
        float val[COUT];
        #pragma unroll
        for (int co=0; co<COUT; ++co) val[co] = acc[co] + bias[co];
        const float inv_s = 1.f/(aff_scale[0] + 1e-5f);
        out[(long)b*HW_ + gy*W_ + gx] =
            deform_px(val, fus + (long)b*HW_, gk + b*8, inv_s, gy, gx);
    } else {
        #pragma unroll
        for (int co=0; co<COUT; ++co){
            float o = acc[co];
            if (OUT_MODE >= 1) o += bias[co];
            if (OUT_MODE == 2) o = tanhf(o);
            out[(((long)b*COUT+co)*H_+gy)*W_+gx] = o;
        }
    }
}

// ---------------------------------------------------------------------------
// Global average pool of feat -> p (B,32). One block per (b,c).
// ---------------------------------------------------------------------------
__global__ void pool_k(const float* __restrict__ feat, float* __restrict__ p){
    const int bc = blockIdx.x;
    const float* src = feat + (long)bc*HW_;
    float s = 0.f;
    for (int i=threadIdx.x; i<HW_; i+=256) s += src[i];
    #pragma unroll
    for (int off=32; off; off>>=1) s += __shfl_down(s, off, 64);
    __shared__ float red[4];
    const int lane = threadIdx.x & 63, wid = threadIdx.x >> 6;
    if (lane == 0) red[wid] = s;
    __syncthreads();
    if (threadIdx.x == 0)
        p[bc] = (red[0]+red[1]+red[2]+red[3]) * (1.f/(float)HW_);
}

// ---------------------------------------------------------------------------
// CAM MLP (32->16 celu ->16 celu ->1 relu +0.001) then gauss_win -> gk (B,8)
// ---------------------------------------------------------------------------
__global__ void sigma_k(const float* __restrict__ p,
                        const float* s1w, const float* s1b,
                        const float* s2w, const float* s2b,
                        const float* s3w, const float* s3b,
                        float* __restrict__ gk){
    const int b = threadIdx.x;
    if (b >= B_) return;
    float h1[16], h2[16];
    for (int i=0;i<16;++i){
        float t = s1b[i];
        for (int j=0;j<32;++j) t = fmaf(p[b*32+j], s1w[i*32+j], t);
        h1[i] = t > 0.f ? t : expm1f(t);          // celu(alpha=1)
    }
    for (int i=0;i<16;++i){
        float t = s2b[i];
        for (int j=0;j<16;++j) t = fmaf(h1[j], s2w[i*16+j], t);
        h2[i] = t > 0.f ? t : expm1f(t);
    }
    float t = s3b[0];
    for (int j=0;j<16;++j) t = fmaf(h2[j], s3w[j], t);
    float sigma = fmaxf(t, 0.f) + 0.001f;
    float sg = sigma + 0.2f;                      // sigma_gamma = 0.2
    float e = expf(-1.f/(2.f*sg*sg));
    float inv = 1.f/(2.f*e + 1.f);
    float a = e*inv, c = inv;                     // w1 = [a, c, a]
    float* g = gk + b*8;                          // outer(w1,w1) flat minus center
    g[0]=a*a; g[1]=a*c; g[2]=a*a; g[3]=c*a; g[4]=c*a; g[5]=a*a; g[6]=a*c; g[7]=a*a;
}

// ---------------------------------------------------------------------------
extern "C" void kernel_launch(void* const* d_in, const int* in_sizes, int n_in,
                              void* d_out, int out_size, void* d_ws, size_t ws_size,
                              hipStream_t stream){
    const float* feat    = (const float*)d_in[0];
    const float* g1_w    = (const float*)d_in[1];
    const float* g1_g    = (const float*)d_in[2];
    const float* g1_b    = (const float*)d_in[3];
    const float* g2_w    = (const float*)d_in[4];
    const float* g2_g    = (const float*)d_in[5];
    const float* g2_b    = (const float*)d_in[6];
    const float* g3_w    = (const float*)d_in[7];
    const float* g3_bias = (const float*)d_in[8];
    const float* f1_w    = (const float*)d_in[9];
    const float* f1_g    = (const float*)d_in[10];
    const float* f1_b    = (const float*)d_in[11];
    const float* f2_w    = (const float*)d_in[12];
    const float* f2_bias = (const float*)d_in[13];
    const float* s1w     = (const float*)d_in[14];
    const float* s1b     = (const float*)d_in[15];
    const float* s2w     = (const float*)d_in[16];
    const float* s2b     = (const float*)d_in[17];
    const float* s3w     = (const float*)d_in[18];
    const float* s3b     = (const float*)d_in[19];
    const float* oa1_w   = (const float*)d_in[20];
    const float* oa1_g   = (const float*)d_in[21];
    const float* oa1_b   = (const float*)d_in[22];
    const float* oa2_w   = (const float*)d_in[23];
    const float* oa2_g   = (const float*)d_in[24];
    const float* oa2_b   = (const float*)d_in[25];
    const float* oa3_w   = (const float*)d_in[26];
    const float* oa3_bias= (const float*)d_in[27];
    const float* aff_scale=(const float*)d_in[28];
    float* out = (float*)d_out;

    // workspace (fp32):
    //   A1   : 32ch  (f1/g1 out; later aliased by OA2 24ch)  104857600 B
    //   A2   : 8ch   (g2 out, then oa1 out)                   26214400 B
    //   GUID : 8ch                                            26214400 B
    //   FUS  : 1ch                                             3276800 B
    //   SM   : stats + p + gk + repacked weights               ~260 KB
    char* ws = (char*)d_ws;
    float* A1   = (float*)(ws + 0L);
    float* A2   = (float*)(ws + 104857600L);
    float* GUID = (float*)(ws + 131072000L);
    float* FUS  = (float*)(ws + 157286400L);
    float* SM   = (float*)(ws + 160563200L);
    float* OA2  = A1;   // alias: A1 dead before oa2 conv writes

    // stats slots: 5 tensors x 64 (sum) + 5 x 64 (sumsq)
    float* sum = SM;             // [5*64]
    float* sq  = SM + 320;       // [5*64]
    float* p   = SM + 640;       // 256
    float* gk  = SM + 896;       // 64
    float* WB  = SM + 960;       // repacked weights, 63904 floats
    float* w_f1 = WB + 0;
    float* w_f2 = WB + 9216;
    float* w_g1 = WB + 9504;
    float* w_g2 = WB + 35104;
    float* w_g3 = WB + 41504;
    float* w_o1 = WB + 43104;
    float* w_o2 = WB + 44704;
    float* w_o3 = WB + 49504;

    hipMemsetAsync(sum, 0, 640*sizeof(float), stream);   // zero sum+sumsq

    repack_all_k<<<dim3(250), dim3(256), 0, stream>>>(
        f1_w, f2_w, g1_w, g2_w, g3_w, oa1_w, oa2_w, oa3_w, WB);

    // sigma branch (independent)
    pool_k<<<dim3(256), dim3(256), 0, stream>>>(feat, p);
    sigma_k<<<dim3(1), dim3(64), 0, stream>>>(p, s1w, s1b, s2w, s2b, s3w, s3b, gk);

    const dim3 cgrid(10, 40, 8), cblk(256);
    #define CONV(CIN,COUT,K,CCH,IBN,OST,OM) conv_k<CIN,COUT,K,CCH,IBN,OST,OM><<<cgrid,cblk,0,stream>>>

    // fuse branch: f1 (3x3 32->32, stats) -> f2 (bn+relu in, 3x3 32->1, tanh)
    CONV(32,32,3,16,false,true ,0)(feat, nullptr, nullptr, nullptr, nullptr,
        w_f1, nullptr, A1, sum+0*64, sq+0*64, nullptr, nullptr, nullptr);
    CONV(32, 1,3,16,true ,false,2)(A1, sum+0*64, sq+0*64, f1_g, f1_b,
        w_f2, f2_bias, FUS, nullptr, nullptr, nullptr, nullptr, nullptr);

    // guid branch: g1 (5x5 32->32, stats) -> g2 (5x5 32->8, stats) -> g3 (5x5 8->8 +bias)
    CONV(32,32,5,16,false,true ,0)(feat, nullptr, nullptr, nullptr, nullptr,
        w_g1, nullptr, A1, sum+1*64, sq+1*64, nullptr, nullptr, nullptr);
    CONV(32, 8,5,16,true ,true ,0)(A1, sum+1*64, sq+1*64, g1_g, g1_b,
        w_g2, nullptr, A2, sum+2*64, sq+2*64, nullptr, nullptr, nullptr);
    CONV( 8, 8,5, 8,true ,false,1)(A2, sum+2*64, sq+2*64, g2_g, g2_b,
        w_g3, g3_bias, GUID, nullptr, nullptr, nullptr, nullptr, nullptr);

    // off_aff branch: oa1 (5x5 8->8, stats) -> oa2 (5x5 8->24, stats)
    //                 -> oa3 (5x5 24->24 +bias) fused with deform -> out
    CONV( 8, 8,5, 8,false,true ,0)(GUID, nullptr, nullptr, nullptr, nullptr,
        w_o1, nullptr, A2, sum+3*64, sq+3*64, nullptr, nullptr, nullptr);
    CONV( 8,24,5, 8,true ,true ,0)(A2, sum+3*64, sq+3*64, oa1_g, oa1_b,
        w_o2, nullptr, OA2, sum+4*64, sq+4*64, nullptr, nullptr, nullptr);
    CONV(24,24,5, 8,true ,false,3)(OA2, sum+4*64, sq+4*64, oa2_g, oa2_b,
        w_o3, oa3_bias, out, nullptr, nullptr, FUS, gk, aff_scale);
    #undef CONV
}

// Round 4
// 2182.394 us; speedup vs baseline: 1.0190x; 1.0190x over previous
//
#include <hip/hip_runtime.h>
#include <hip/hip_bf16.h>
#include <math.h>

#define B_   8
#define H_   320
#define W_   320
#define HW_  (320*320)

// ---------------------------------------------------------------------------
// Repack ALL conv weights in one dispatch:
// [co][ci][ky][kx] -> [ci*K*K + ky*K + kx][co], 8 segments.
// ---------------------------------------------------------------------------
__global__ void repack_all_k(const float* __restrict__ sf1, const float* __restrict__ sf2,
                             const float* __restrict__ sg1, const float* __restrict__ sg2,
                             const float* __restrict__ sg3, const float* __restrict__ so1,
                             const float* __restrict__ so2, const float* __restrict__ so3,
                             float* __restrict__ dst){
    const int cum[8]  = {9216, 9504, 35104, 41504, 43104, 44704, 49504, 63904};
    const int cout[8] = {32, 1, 32, 8, 8, 8, 24, 24};
    const int ckk[8]  = {288, 288, 800, 800, 200, 200, 200, 600};
    const int doff[8] = {0, 9216, 9504, 35104, 41504, 43104, 44704, 49504};
    int i = blockIdx.x*256 + threadIdx.x;
    if (i >= 63904) return;
    int s = 0;
    while (i >= cum[s]) ++s;
    const int base = s ? cum[s-1] : 0;
    const int il = i - base;
    const float* src = (s==0)?sf1:(s==1)?sf2:(s==2)?sg1:(s==3)?sg2:(s==4)?sg3:(s==5)?so1:(s==6)?so2:so3;
    const int co = il / ckk[s];
    const int t  = il - co*ckk[s];
    dst[doff[s] + t*cout[s] + co] = src[il];
}

// ---------------------------------------------------------------------------
// Deform epilogue (device): given this pixel's 24 oa3 values (+bias applied),
// sample fusion with deformable 3x3 + gaussian-affinity mask, return |.|
// ---------------------------------------------------------------------------
__device__ __forceinline__
float deform_px(const float* val, const float* __restrict__ fus_b,
                const float* __restrict__ gk_b, float inv_s, int y, int x){
    float aff[8]; float sa = 0.f;
    #pragma unroll
    for (int n=0;n<8;++n){
        float a = tanhf(val[16+n]) * inv_s + gk_b[n];
        aff[n] = a; sa += fabsf(a);
    }
    sa += 1e-5f;
    sa = fmaxf(sa, 1.f);
    const float isa = 1.f/sa;
    float ssum = 0.f;
    #pragma unroll
    for (int n=0;n<8;++n){ aff[n] *= isa; ssum += aff[n]; }
    const float aff_ref = 1.f - ssum;

    float o = 0.f;
    #pragma unroll
    for (int k=0;k<9;++k){
        float dy, dx, m;
        if (k == 4){ dy = 0.f; dx = 0.f; m = aff_ref; }
        else {
            const int n = (k < 4) ? k : k-1;
            dy = val[2*n];
            dx = val[2*n+1];
            m  = aff[n];
        }
        float yy = (float)(y + k/3 - 1) + dy;
        float xx = (float)(x + k%3 - 1) + dx;
        float y0f = floorf(yy), x0f = floorf(xx);
        int   y0 = (int)y0f,    x0i = (int)x0f;
        float wy1 = yy - y0f, wy0 = 1.f - wy1;
        float wx1 = xx - x0f, wx0 = 1.f - wx1;
        float v00 = (y0  >=0 && y0  <H_ && x0i  >=0 && x0i  <W_) ? fus_b[ y0   *W_ + x0i  ] : 0.f;
        float v01 = (y0  >=0 && y0  <H_ && x0i+1>=0 && x0i+1<W_) ? fus_b[ y0   *W_ + x0i+1] : 0.f;
        float v10 = (y0+1>=0 && y0+1<H_ && x0i  >=0 && x0i  <W_) ? fus_b[(y0+1)*W_ + x0i  ] : 0.f;
        float v11 = (y0+1>=0 && y0+1<H_ && x0i+1>=0 && x0i+1<W_) ? fus_b[(y0+1)*W_ + x0i+1] : 0.f;
        o += m * (wy0*(wx0*v00 + wx1*v01) + wy1*(wx0*v10 + wx1*v11));
    }
    return fabsf(o);
}

// ---------------------------------------------------------------------------
// Fused direct conv.
//   IN_BN:  compute scale/shift in-kernel from producer's (sum,sumsq) + gamma/
//           beta, apply y=relu(x*sc+sh) at LDS-load time (halo zeroed after).
//   OUT_STATS: epilogue per-channel (sum,sumsq) via wave shuffle + LDS + one
//           atomicAdd per block per channel.
//   OUT_MODE: 0 raw, 1 +bias, 2 tanh(x+bias), 3 deform epilogue (+bias).
// 32x8 px tile per block, 256 threads, CCH=8-channel LDS chunks.
// CCH=8 (13.8 KB LDS for K=5): keeps ~5 blocks/CU resident — CCH=16 (28.7 KB)
// dropped occupancy 63%->37% and regressed g1 479->672 us (round 3).
// ---------------------------------------------------------------------------
template<int CIN, int COUT, int K, bool IN_BN, bool OUT_STATS, int OUT_MODE>
__global__ __launch_bounds__(256)
void conv_k(const float* __restrict__ in,
            const float* __restrict__ bn_sum, const float* __restrict__ bn_sq,
            const float* __restrict__ gamma, const float* __restrict__ beta,
            const float* __restrict__ w, const float* __restrict__ bias,
            float* __restrict__ out,
            float* __restrict__ osum, float* __restrict__ osq,
            const float* __restrict__ fus, const float* __restrict__ gk,
            const float* __restrict__ aff_scale){
    constexpr int PAD = K/2;
    constexpr int LW  = 32 + K - 1;
    constexpr int LH  = 8 + K - 1;
    constexpr int PS  = LW*LH;
    constexpr int CCH = 8;
    __shared__ float lds[CCH*PS];
    __shared__ float sc_sh[2][CIN];
    __shared__ float red[OUT_STATS ? 8*COUT : 1];

    const int tid = threadIdx.x;
    const int b   = blockIdx.z;
    const int x0 = blockIdx.x*32, y0 = blockIdx.y*8;

    if (IN_BN){
        if (tid < CIN){
            const float invN = 1.f/(float)(B_*HW_);
            float mu  = bn_sum[tid]*invN;
            float var = bn_sq[tid]*invN - mu*mu;
            float s = gamma[tid] * rsqrtf(var + 1e-5f);
            sc_sh[0][tid] = s;
            sc_sh[1][tid] = beta[tid] - mu*s;
        }
        __syncthreads();
    }

    float acc[COUT];
    #pragma unroll
    for (int i=0;i<COUT;++i) acc[i] = 0.f;

    const int lane  = tid & 31;
    const int pslot = tid >> 5;
    const int tx = tid & 31, ty = tid >> 5;

    for (int c0=0; c0<CIN; c0+=CCH){
        if (c0) __syncthreads();
        // ---- stage CCH input planes (one plane per 32-lane slot) ----
        {
            const int pl = pslot;
            const int ci = c0 + pl;
            float sc = 1.f, sh = 0.f;
            if (IN_BN){ sc = sc_sh[0][ci]; sh = sc_sh[1][ci]; }
            const float* src = in + ((long)b*CIN + ci)*HW_;
            float* dst = lds + pl*PS;
            #pragma unroll
            for (int r=0; r<LH; ++r){
                const int gy = y0 + r - PAD;
                const bool rowok = (gy>=0) & (gy<H_);
                {
                    const int gx = x0 + lane - PAD;
                    float v = 0.f;
                    if (rowok && gx>=0 && gx<W_){
                        v = src[gy*W_ + gx];
                        if (IN_BN) v = fmaxf(fmaf(v, sc, sh), 0.f);
                    }
                    dst[r*LW + lane] = v;
                }
                if (lane < LW-32){
                    const int col = lane + 32;
                    const int gx = x0 + col - PAD;
                    float v = 0.f;
                    if (rowok && gx>=0 && gx<W_){
                        v = src[gy*W_ + gx];
                        if (IN_BN) v = fmaxf(fmaf(v, sc, sh), 0.f);
                    }
                    dst[r*LW + col] = v;
                }
            }
        }
        __syncthreads();
        // ---- compute ----
        for (int pl=0; pl<CCH; ++pl){
            const float* wb = w + (long)(c0+pl)*(K*K*COUT);
            const float* lp = lds + pl*PS + ty*LW + tx;
            #pragma unroll
            for (int ky=0; ky<K; ++ky){
                #pragma unroll
                for (int kx=0; kx<K; ++kx){
                    const float v = lp[ky*LW + kx];
                    const float* wt = wb + (ky*K+kx)*COUT;
                    #pragma unroll
                    for (int co=0; co<COUT; ++co)
                        acc[co] = fmaf(v, wt[co], acc[co]);
                }
            }
        }
    }

    // ---- fused BN-stats epilogue (on raw pre-bias acc) ----
    if (OUT_STATS){
        const int wid = tid >> 6, wl = tid & 63;
        #pragma unroll
        for (int co=0; co<COUT; ++co){
            float v = acc[co], v2 = v*v;
            #pragma unroll
            for (int off=32; off; off>>=1){
                v  += __shfl_down(v,  off, 64);
                v2 += __shfl_down(v2, off, 64);
            }
            if (wl == 0){
                red[(wid*COUT+co)*2  ] = v;
                red[(wid*COUT+co)*2+1] = v2;
            }
        }
        __syncthreads();
        if (tid < COUT){
            float s  = red[tid*2]          + red[(COUT+tid)*2]
                     + red[(2*COUT+tid)*2] + red[(3*COUT+tid)*2];
            float s2 = red[tid*2+1]          + red[(COUT+tid)*2+1]
                     + red[(2*COUT+tid)*2+1] + red[(3*COUT+tid)*2+1];
            atomicAdd(&osum[tid], s);
            atomicAdd(&osq[tid],  s2);
        }
    }

    const int gy = y0+ty, gx = x0+tx;
    if (OUT_MODE == 3){
        // oa3 + deform fused: acc[24]+bias are this px's oa3 channels
        float val[COUT];
        #pragma unroll
        for (int co=0; co<COUT; ++co) val[co] = acc[co] + bias[co];
        const float inv_s = 1.f/(aff_scale[0] + 1e-5f);
        out[(long)b*HW_ + gy*W_ + gx] =
            deform_px(val, fus + (long)b*HW_, gk + b*8, inv_s, gy, gx);
    } else {
        #pragma unroll
        for (int co=0; co<COUT; ++co){
            float o = acc[co];
            if (OUT_MODE >= 1) o += bias[co];
            if (OUT_MODE == 2) o = tanhf(o);
            out[(((long)b*COUT+co)*H_+gy)*W_+gx] = o;
        }
    }
}

// ---------------------------------------------------------------------------
// Global average pool of feat -> p (B,32). One block per (b,c).
// ---------------------------------------------------------------------------
__global__ void pool_k(const float* __restrict__ feat, float* __restrict__ p){
    const int bc = blockIdx.x;
    const float* src = feat + (long)bc*HW_;
    float s = 0.f;
    for (int i=threadIdx.x; i<HW_; i+=256) s += src[i];
    #pragma unroll
    for (int off=32; off; off>>=1) s += __shfl_down(s, off, 64);
    __shared__ float red[4];
    const int lane = threadIdx.x & 63, wid = threadIdx.x >> 6;
    if (lane == 0) red[wid] = s;
    __syncthreads();
    if (threadIdx.x == 0)
        p[bc] = (red[0]+red[1]+red[2]+red[3]) * (1.f/(float)HW_);
}

// ---------------------------------------------------------------------------
// CAM MLP (32->16 celu ->16 celu ->1 relu +0.001) then gauss_win -> gk (B,8)
// ---------------------------------------------------------------------------
__global__ void sigma_k(const float* __restrict__ p,
                        const float* s1w, const float* s1b,
                        const float* s2w, const float* s2b,
                        const float* s3w, const float* s3b,
                        float* __restrict__ gk){
    const int b = threadIdx.x;
    if (b >= B_) return;
    float h1[16], h2[16];
    for (int i=0;i<16;++i){
        float t = s1b[i];
        for (int j=0;j<32;++j) t = fmaf(p[b*32+j], s1w[i*32+j], t);
        h1[i] = t > 0.f ? t : expm1f(t);          // celu(alpha=1)
    }
    for (int i=0;i<16;++i){
        float t = s2b[i];
        for (int j=0;j<16;++j) t = fmaf(h1[j], s2w[i*16+j], t);
        h2[i] = t > 0.f ? t : expm1f(t);
    }
    float t = s3b[0];
    for (int j=0;j<16;++j) t = fmaf(h2[j], s3w[j], t);
    float sigma = fmaxf(t, 0.f) + 0.001f;
    float sg = sigma + 0.2f;                      // sigma_gamma = 0.2
    float e = expf(-1.f/(2.f*sg*sg));
    float inv = 1.f/(2.f*e + 1.f);
    float a = e*inv, c = inv;                     // w1 = [a, c, a]
    float* g = gk + b*8;                          // outer(w1,w1) flat minus center
    g[0]=a*a; g[1]=a*c; g[2]=a*a; g[3]=c*a; g[4]=c*a; g[5]=a*a; g[6]=a*c; g[7]=a*a;
}

// ---------------------------------------------------------------------------
extern "C" void kernel_launch(void* const* d_in, const int* in_sizes, int n_in,
                              void* d_out, int out_size, void* d_ws, size_t ws_size,
                              hipStream_t stream){
    const float* feat    = (const float*)d_in[0];
    const float* g1_w    = (const float*)d_in[1];
    const float* g1_g    = (const float*)d_in[2];
    const float* g1_b    = (const float*)d_in[3];
    const float* g2_w    = (const float*)d_in[4];
    const float* g2_g    = (const float*)d_in[5];
    const float* g2_b    = (const float*)d_in[6];
    const float* g3_w    = (const float*)d_in[7];
    const float* g3_bias = (const float*)d_in[8];
    const float* f1_w    = (const float*)d_in[9];
    const float* f1_g    = (const float*)d_in[10];
    const float* f1_b    = (const float*)d_in[11];
    const float* f2_w    = (const float*)d_in[12];
    const float* f2_bias = (const float*)d_in[13];
    const float* s1w     = (const float*)d_in[14];
    const float* s1b     = (const float*)d_in[15];
    const float* s2w     = (const float*)d_in[16];
    const float* s2b     = (const float*)d_in[17];
    const float* s3w     = (const float*)d_in[18];
    const float* s3b     = (const float*)d_in[19];
    const float* oa1_w   = (const float*)d_in[20];
    const float* oa1_g   = (const float*)d_in[21];
    const float* oa1_b   = (const float*)d_in[22];
    const float* oa2_w   = (const float*)d_in[23];
    const float* oa2_g   = (const float*)d_in[24];
    const float* oa2_b   = (const float*)d_in[25];
    const float* oa3_w   = (const float*)d_in[26];
    const float* oa3_bias= (const float*)d_in[27];
    const float* aff_scale=(const float*)d_in[28];
    float* out = (float*)d_out;

    // workspace (fp32):
    //   A1   : 32ch  (f1/g1 out; later aliased by OA2 24ch)  104857600 B
    //   A2   : 8ch   (g2 out, then oa1 out)                   26214400 B
    //   GUID : 8ch                                            26214400 B
    //   FUS  : 1ch                                             3276800 B
    //   SM   : stats + p + gk + repacked weights               ~260 KB
    char* ws = (char*)d_ws;
    float* A1   = (float*)(ws + 0L);
    float* A2   = (float*)(ws + 104857600L);
    float* GUID = (float*)(ws + 131072000L);
    float* FUS  = (float*)(ws + 157286400L);
    float* SM   = (float*)(ws + 160563200L);
    float* OA2  = A1;   // alias: A1 dead before oa2 conv writes

    // stats slots: 5 tensors x 64 (sum) + 5 x 64 (sumsq)
    float* sum = SM;             // [5*64]
    float* sq  = SM + 320;       // [5*64]
    float* p   = SM + 640;       // 256
    float* gk  = SM + 896;       // 64
    float* WB  = SM + 960;       // repacked weights, 63904 floats
    float* w_f1 = WB + 0;
    float* w_f2 = WB + 9216;
    float* w_g1 = WB + 9504;
    float* w_g2 = WB + 35104;
    float* w_g3 = WB + 41504;
    float* w_o1 = WB + 43104;
    float* w_o2 = WB + 44704;
    float* w_o3 = WB + 49504;

    hipMemsetAsync(sum, 0, 640*sizeof(float), stream);   // zero sum+sumsq

    repack_all_k<<<dim3(250), dim3(256), 0, stream>>>(
        f1_w, f2_w, g1_w, g2_w, g3_w, oa1_w, oa2_w, oa3_w, WB);

    // sigma branch (independent)
    pool_k<<<dim3(256), dim3(256), 0, stream>>>(feat, p);
    sigma_k<<<dim3(1), dim3(64), 0, stream>>>(p, s1w, s1b, s2w, s2b, s3w, s3b, gk);

    const dim3 cgrid(10, 40, 8), cblk(256);
    #define CONV(CIN,COUT,K,IBN,OST,OM) conv_k<CIN,COUT,K,IBN,OST,OM><<<cgrid,cblk,0,stream>>>

    // fuse branch: f1 (3x3 32->32, stats) -> f2 (bn+relu in, 3x3 32->1, tanh)
    CONV(32,32,3,false,true ,0)(feat, nullptr, nullptr, nullptr, nullptr,
        w_f1, nullptr, A1, sum+0*64, sq+0*64, nullptr, nullptr, nullptr);
    CONV(32, 1,3,true ,false,2)(A1, sum+0*64, sq+0*64, f1_g, f1_b,
        w_f2, f2_bias, FUS, nullptr, nullptr, nullptr, nullptr, nullptr);

    // guid branch: g1 (5x5 32->32, stats) -> g2 (5x5 32->8, stats) -> g3 (5x5 8->8 +bias)
    CONV(32,32,5,false,true ,0)(feat, nullptr, nullptr, nullptr, nullptr,
        w_g1, nullptr, A1, sum+1*64, sq+1*64, nullptr, nullptr, nullptr);
    CONV(32, 8,5,true ,true ,0)(A1, sum+1*64, sq+1*64, g1_g, g1_b,
        w_g2, nullptr, A2, sum+2*64, sq+2*64, nullptr, nullptr, nullptr);
    CONV( 8, 8,5,true ,false,1)(A2, sum+2*64, sq+2*64, g2_g, g2_b,
        w_g3, g3_bias, GUID, nullptr, nullptr, nullptr, nullptr, nullptr);

    // off_aff branch: oa1 (5x5 8->8, stats) -> oa2 (5x5 8->24, stats)
    //                 -> oa3 (5x5 24->24 +bias) fused with deform -> out
    CONV( 8, 8,5,false,true ,0)(GUID, nullptr, nullptr, nullptr, nullptr,
        w_o1, nullptr, A2, sum+3*64, sq+3*64, nullptr, nullptr, nullptr);
    CONV( 8,24,5,true ,true ,0)(A2, sum+3*64, sq+3*64, oa1_g, oa1_b,
        w_o2, nullptr, OA2, sum+4*64, sq+4*64, nullptr, nullptr, nullptr);
    CONV(24,24,5,true ,false,3)(OA2, sum+4*64, sq+4*64, oa2_g, oa2_b,
        w_o3, oa3_bias, out, nullptr, nullptr, FUS, gk, aff_scale);
    #undef CONV
}

// Round 5
// 1898.057 us; speedup vs baseline: 1.1717x; 1.1498x over previous
//
#include <hip/hip_runtime.h>
#include <hip/hip_bf16.h>
#include <math.h>

#define B_   8
#define H_   320
#define W_   320
#define HW_  (320*320)

// ---------------------------------------------------------------------------
// Repack ALL conv weights in one dispatch:
// [co][ci][ky][kx] -> [ci*K*K + ky*K + kx][co], 8 segments.
// ---------------------------------------------------------------------------
__global__ void repack_all_k(const float* __restrict__ sf1, const float* __restrict__ sf2,
                             const float* __restrict__ sg1, const float* __restrict__ sg2,
                             const float* __restrict__ sg3, const float* __restrict__ so1,
                             const float* __restrict__ so2, const float* __restrict__ so3,
                             float* __restrict__ dst){
    const int cum[8]  = {9216, 9504, 35104, 41504, 43104, 44704, 49504, 63904};
    const int cout[8] = {32, 1, 32, 8, 8, 8, 24, 24};
    const int ckk[8]  = {288, 288, 800, 800, 200, 200, 200, 600};
    const int doff[8] = {0, 9216, 9504, 35104, 41504, 43104, 44704, 49504};
    int i = blockIdx.x*256 + threadIdx.x;
    if (i >= 63904) return;
    int s = 0;
    while (i >= cum[s]) ++s;
    const int base = s ? cum[s-1] : 0;
    const int il = i - base;
    const float* src = (s==0)?sf1:(s==1)?sf2:(s==2)?sg1:(s==3)?sg2:(s==4)?sg3:(s==5)?so1:(s==6)?so2:so3;
    const int co = il / ckk[s];
    const int t  = il - co*ckk[s];
    dst[doff[s] + t*cout[s] + co] = src[il];
}

// ---------------------------------------------------------------------------
// Deform epilogue (device): given this pixel's 24 oa3 values (+bias applied),
// sample fusion with deformable 3x3 + gaussian-affinity mask, return |.|
// ---------------------------------------------------------------------------
__device__ __forceinline__
float deform_px(const float* val, const float* __restrict__ fus_b,
                const float* __restrict__ gk_b, float inv_s, int y, int x){
    float aff[8]; float sa = 0.f;
    #pragma unroll
    for (int n=0;n<8;++n){
        float a = tanhf(val[16+n]) * inv_s + gk_b[n];
        aff[n] = a; sa += fabsf(a);
    }
    sa += 1e-5f;
    sa = fmaxf(sa, 1.f);
    const float isa = 1.f/sa;
    float ssum = 0.f;
    #pragma unroll
    for (int n=0;n<8;++n){ aff[n] *= isa; ssum += aff[n]; }
    const float aff_ref = 1.f - ssum;

    float o = 0.f;
    #pragma unroll
    for (int k=0;k<9;++k){
        float dy, dx, m;
        if (k == 4){ dy = 0.f; dx = 0.f; m = aff_ref; }
        else {
            const int n = (k < 4) ? k : k-1;
            dy = val[2*n];
            dx = val[2*n+1];
            m  = aff[n];
        }
        float yy = (float)(y + k/3 - 1) + dy;
        float xx = (float)(x + k%3 - 1) + dx;
        float y0f = floorf(yy), x0f = floorf(xx);
        int   y0 = (int)y0f,    x0i = (int)x0f;
        float wy1 = yy - y0f, wy0 = 1.f - wy1;
        float wx1 = xx - x0f, wx0 = 1.f - wx1;
        float v00 = (y0  >=0 && y0  <H_ && x0i  >=0 && x0i  <W_) ? fus_b[ y0   *W_ + x0i  ] : 0.f;
        float v01 = (y0  >=0 && y0  <H_ && x0i+1>=0 && x0i+1<W_) ? fus_b[ y0   *W_ + x0i+1] : 0.f;
        float v10 = (y0+1>=0 && y0+1<H_ && x0i  >=0 && x0i  <W_) ? fus_b[(y0+1)*W_ + x0i  ] : 0.f;
        float v11 = (y0+1>=0 && y0+1<H_ && x0i+1>=0 && x0i+1<W_) ? fus_b[(y0+1)*W_ + x0i+1] : 0.f;
        o += m * (wy0*(wx0*v00 + wx1*v01) + wy1*(wx0*v10 + wx1*v11));
    }
    return fabsf(o);
}

// ---------------------------------------------------------------------------
// Fused direct conv.
//   IN_BN:  compute scale/shift in-kernel from producer's (sum,sumsq) + gamma/
//           beta, apply y=relu(x*sc+sh) at LDS-load time (halo zeroed after).
//   OUT_STATS: epilogue per-channel (sum,sumsq) via wave shuffle + LDS + one
//           atomicAdd per block per channel.
//   OUT_MODE: 0 raw, 1 +bias, 2 tanh(x+bias), 3 deform epilogue (+bias).
// 32x8 px tile per block, 256 threads, CCH=8-channel LDS chunks.
// NOTE (r3/r4 lesson): staging MUST be the flat strided loop below. The
// unrolled per-row variant held ~24 loads in flight, VGPR 32->60 units,
// occupancy 63->37%, g1 479->672 us. CCH=16 similarly kills occupancy.
// ---------------------------------------------------------------------------
template<int CIN, int COUT, int K, bool IN_BN, bool OUT_STATS, int OUT_MODE>
__global__ __launch_bounds__(256, 5)
void conv_k(const float* __restrict__ in,
            const float* __restrict__ bn_sum, const float* __restrict__ bn_sq,
            const float* __restrict__ gamma, const float* __restrict__ beta,
            const float* __restrict__ w, const float* __restrict__ bias,
            float* __restrict__ out,
            float* __restrict__ osum, float* __restrict__ osq,
            const float* __restrict__ fus, const float* __restrict__ gk,
            const float* __restrict__ aff_scale){
    constexpr int PAD = K/2;
    constexpr int LW  = 32 + K - 1;
    constexpr int LH  = 8 + K - 1;
    constexpr int PS  = LW*LH;
    constexpr int CCH = 8;
    __shared__ float lds[CCH*PS];
    __shared__ float sc_sh[2][CIN];
    __shared__ float red[OUT_STATS ? 8*COUT : 1];

    const int tid = threadIdx.x;
    const int b   = blockIdx.z;
    const int x0 = blockIdx.x*32, y0 = blockIdx.y*8;

    if (IN_BN){
        if (tid < CIN){
            const float invN = 1.f/(float)(B_*HW_);
            float mu  = bn_sum[tid]*invN;
            float var = bn_sq[tid]*invN - mu*mu;
            float s = gamma[tid] * rsqrtf(var + 1e-5f);
            sc_sh[0][tid] = s;
            sc_sh[1][tid] = beta[tid] - mu*s;
        }
        __syncthreads();
    }

    float acc[COUT];
    #pragma unroll
    for (int i=0;i<COUT;++i) acc[i] = 0.f;

    const int tx = tid & 31, ty = tid >> 5;

    for (int c0=0; c0<CIN; c0+=CCH){
        if (c0) __syncthreads();
        // ---- stage CCH input planes: flat strided loop (low reg pressure) ----
        for (int i=tid; i<CCH*PS; i+=256){
            const int pl  = i / PS;
            const int rem = i - pl*PS;
            const int r   = rem / LW;
            const int cc  = rem - r*LW;
            const int gy = y0 + r - PAD, gx = x0 + cc - PAD;
            float v = 0.f;
            if (gy>=0 && gy<H_ && gx>=0 && gx<W_){
                const int ci = c0 + pl;
                v = in[(((long)b*CIN + ci)*H_ + gy)*W_ + gx];
                if (IN_BN) v = fmaxf(fmaf(v, sc_sh[0][ci], sc_sh[1][ci]), 0.f);
            }
            lds[i] = v;
        }
        __syncthreads();
        // ---- compute ----
        for (int pl=0; pl<CCH; ++pl){
            const float* wb = w + (long)(c0+pl)*(K*K*COUT);
            const float* lp = lds + pl*PS + ty*LW + tx;
            #pragma unroll
            for (int ky=0; ky<K; ++ky){
                #pragma unroll
                for (int kx=0; kx<K; ++kx){
                    const float v = lp[ky*LW + kx];
                    const float* wt = wb + (ky*K+kx)*COUT;
                    #pragma unroll
                    for (int co=0; co<COUT; ++co)
                        acc[co] = fmaf(v, wt[co], acc[co]);
                }
            }
        }
    }

    // ---- fused BN-stats epilogue (on raw pre-bias acc) ----
    if (OUT_STATS){
        const int wid = tid >> 6, wl = tid & 63;
        #pragma unroll
        for (int co=0; co<COUT; ++co){
            float v = acc[co], v2 = v*v;
            #pragma unroll
            for (int off=32; off; off>>=1){
                v  += __shfl_down(v,  off, 64);
                v2 += __shfl_down(v2, off, 64);
            }
            if (wl == 0){
                red[(wid*COUT+co)*2  ] = v;
                red[(wid*COUT+co)*2+1] = v2;
            }
        }
        __syncthreads();
        if (tid < COUT){
            float s  = red[tid*2]          + red[(COUT+tid)*2]
                     + red[(2*COUT+tid)*2] + red[(3*COUT+tid)*2];
            float s2 = red[tid*2+1]          + red[(COUT+tid)*2+1]
                     + red[(2*COUT+tid)*2+1] + red[(3*COUT+tid)*2+1];
            atomicAdd(&osum[tid], s);
            atomicAdd(&osq[tid],  s2);
        }
    }

    const int gy = y0+ty, gx = x0+tx;
    if (OUT_MODE == 3){
        // oa3 + deform fused: acc[24]+bias are this px's oa3 channels
        float val[COUT];
        #pragma unroll
        for (int co=0; co<COUT; ++co) val[co] = acc[co] + bias[co];
        const float inv_s = 1.f/(aff_scale[0] + 1e-5f);
        out[(long)b*HW_ + gy*W_ + gx] =
            deform_px(val, fus + (long)b*HW_, gk + b*8, inv_s, gy, gx);
    } else {
        #pragma unroll
        for (int co=0; co<COUT; ++co){
            float o = acc[co];
            if (OUT_MODE >= 1) o += bias[co];
            if (OUT_MODE == 2) o = tanhf(o);
            out[(((long)b*COUT+co)*H_+gy)*W_+gx] = o;
        }
    }
}

// ---------------------------------------------------------------------------
// Global average pool of feat -> p (B,32). One block per (b,c).
// ---------------------------------------------------------------------------
__global__ void pool_k(const float* __restrict__ feat, float* __restrict__ p){
    const int bc = blockIdx.x;
    const float* src = feat + (long)bc*HW_;
    float s = 0.f;
    for (int i=threadIdx.x; i<HW_; i+=256) s += src[i];
    #pragma unroll
    for (int off=32; off; off>>=1) s += __shfl_down(s, off, 64);
    __shared__ float red[4];
    const int lane = threadIdx.x & 63, wid = threadIdx.x >> 6;
    if (lane == 0) red[wid] = s;
    __syncthreads();
    if (threadIdx.x == 0)
        p[bc] = (red[0]+red[1]+red[2]+red[3]) * (1.f/(float)HW_);
}

// ---------------------------------------------------------------------------
// CAM MLP (32->16 celu ->16 celu ->1 relu +0.001) then gauss_win -> gk (B,8)
// ---------------------------------------------------------------------------
__global__ void sigma_k(const float* __restrict__ p,
                        const float* s1w, const float* s1b,
                        const float* s2w, const float* s2b,
                        const float* s3w, const float* s3b,
                        float* __restrict__ gk){
    const int b = threadIdx.x;
    if (b >= B_) return;
    float h1[16], h2[16];
    for (int i=0;i<16;++i){
        float t = s1b[i];
        for (int j=0;j<32;++j) t = fmaf(p[b*32+j], s1w[i*32+j], t);
        h1[i] = t > 0.f ? t : expm1f(t);          // celu(alpha=1)
    }
    for (int i=0;i<16;++i){
        float t = s2b[i];
        for (int j=0;j<16;++j) t = fmaf(h1[j], s2w[i*16+j], t);
        h2[i] = t > 0.f ? t : expm1f(t);
    }
    float t = s3b[0];
    for (int j=0;j<16;++j) t = fmaf(h2[j], s3w[j], t);
    float sigma = fmaxf(t, 0.f) + 0.001f;
    float sg = sigma + 0.2f;                      // sigma_gamma = 0.2
    float e = expf(-1.f/(2.f*sg*sg));
    float inv = 1.f/(2.f*e + 1.f);
    float a = e*inv, c = inv;                     // w1 = [a, c, a]
    float* g = gk + b*8;                          // outer(w1,w1) flat minus center
    g[0]=a*a; g[1]=a*c; g[2]=a*a; g[3]=c*a; g[4]=c*a; g[5]=a*a; g[6]=a*c; g[7]=a*a;
}

// ---------------------------------------------------------------------------
extern "C" void kernel_launch(void* const* d_in, const int* in_sizes, int n_in,
                              void* d_out, int out_size, void* d_ws, size_t ws_size,
                              hipStream_t stream){
    const float* feat    = (const float*)d_in[0];
    const float* g1_w    = (const float*)d_in[1];
    const float* g1_g    = (const float*)d_in[2];
    const float* g1_b    = (const float*)d_in[3];
    const float* g2_w    = (const float*)d_in[4];
    const float* g2_g    = (const float*)d_in[5];
    const float* g2_b    = (const float*)d_in[6];
    const float* g3_w    = (const float*)d_in[7];
    const float* g3_bias = (const float*)d_in[8];
    const float* f1_w    = (const float*)d_in[9];
    const float* f1_g    = (const float*)d_in[10];
    const float* f1_b    = (const float*)d_in[11];
    const float* f2_w    = (const float*)d_in[12];
    const float* f2_bias = (const float*)d_in[13];
    const float* s1w     = (const float*)d_in[14];
    const float* s1b     = (const float*)d_in[15];
    const float* s2w     = (const float*)d_in[16];
    const float* s2b     = (const float*)d_in[17];
    const float* s3w     = (const float*)d_in[18];
    const float* s3b     = (const float*)d_in[19];
    const float* oa1_w   = (const float*)d_in[20];
    const float* oa1_g   = (const float*)d_in[21];
    const float* oa1_b   = (const float*)d_in[22];
    const float* oa2_w   = (const float*)d_in[23];
    const float* oa2_g   = (const float*)d_in[24];
    const float* oa2_b   = (const float*)d_in[25];
    const float* oa3_w   = (const float*)d_in[26];
    const float* oa3_bias= (const float*)d_in[27];
    const float* aff_scale=(const float*)d_in[28];
    float* out = (float*)d_out;

    // workspace (fp32):
    //   A1   : 32ch  (f1/g1 out; later aliased by OA2 24ch)  104857600 B
    //   A2   : 8ch   (g2 out, then oa1 out)                   26214400 B
    //   GUID : 8ch                                            26214400 B
    //   FUS  : 1ch                                             3276800 B
    //   SM   : stats + p + gk + repacked weights               ~260 KB
    char* ws = (char*)d_ws;
    float* A1   = (float*)(ws + 0L);
    float* A2   = (float*)(ws + 104857600L);
    float* GUID = (float*)(ws + 131072000L);
    float* FUS  = (float*)(ws + 157286400L);
    float* SM   = (float*)(ws + 160563200L);
    float* OA2  = A1;   // alias: A1 dead before oa2 conv writes

    // stats slots: 5 tensors x 64 (sum) + 5 x 64 (sumsq)
    float* sum = SM;             // [5*64]
    float* sq  = SM + 320;       // [5*64]
    float* p   = SM + 640;       // 256
    float* gk  = SM + 896;       // 64
    float* WB  = SM + 960;       // repacked weights, 63904 floats
    float* w_f1 = WB + 0;
    float* w_f2 = WB + 9216;
    float* w_g1 = WB + 9504;
    float* w_g2 = WB + 35104;
    float* w_g3 = WB + 41504;
    float* w_o1 = WB + 43104;
    float* w_o2 = WB + 44704;
    float* w_o3 = WB + 49504;

    hipMemsetAsync(sum, 0, 640*sizeof(float), stream);   // zero sum+sumsq

    repack_all_k<<<dim3(250), dim3(256), 0, stream>>>(
        f1_w, f2_w, g1_w, g2_w, g3_w, oa1_w, oa2_w, oa3_w, WB);

    // sigma branch (independent)
    pool_k<<<dim3(256), dim3(256), 0, stream>>>(feat, p);
    sigma_k<<<dim3(1), dim3(64), 0, stream>>>(p, s1w, s1b, s2w, s2b, s3w, s3b, gk);

    const dim3 cgrid(10, 40, 8), cblk(256);
    #define CONV(CIN,COUT,K,IBN,OST,OM) conv_k<CIN,COUT,K,IBN,OST,OM><<<cgrid,cblk,0,stream>>>

    // fuse branch: f1 (3x3 32->32, stats) -> f2 (bn+relu in, 3x3 32->1, tanh)
    CONV(32,32,3,false,true ,0)(feat, nullptr, nullptr, nullptr, nullptr,
        w_f1, nullptr, A1, sum+0*64, sq+0*64, nullptr, nullptr, nullptr);
    CONV(32, 1,3,true ,false,2)(A1, sum+0*64, sq+0*64, f1_g, f1_b,
        w_f2, f2_bias, FUS, nullptr, nullptr, nullptr, nullptr, nullptr);

    // guid branch: g1 (5x5 32->32, stats) -> g2 (5x5 32->8, stats) -> g3 (5x5 8->8 +bias)
    CONV(32,32,5,false,true ,0)(feat, nullptr, nullptr, nullptr, nullptr,
        w_g1, nullptr, A1, sum+1*64, sq+1*64, nullptr, nullptr, nullptr);
    CONV(32, 8,5,true ,true ,0)(A1, sum+1*64, sq+1*64, g1_g, g1_b,
        w_g2, nullptr, A2, sum+2*64, sq+2*64, nullptr, nullptr, nullptr);
    CONV( 8, 8,5,true ,false,1)(A2, sum+2*64, sq+2*64, g2_g, g2_b,
        w_g3, g3_bias, GUID, nullptr, nullptr, nullptr, nullptr, nullptr);

    // off_aff branch: oa1 (5x5 8->8, stats) -> oa2 (5x5 8->24, stats)
    //                 -> oa3 (5x5 24->24 +bias) fused with deform -> out
    CONV( 8, 8,5,false,true ,0)(GUID, nullptr, nullptr, nullptr, nullptr,
        w_o1, nullptr, A2, sum+3*64, sq+3*64, nullptr, nullptr, nullptr);
    CONV( 8,24,5,true ,true ,0)(A2, sum+3*64, sq+3*64, oa1_g, oa1_b,
        w_o2, nullptr, OA2, sum+4*64, sq+4*64, nullptr, nullptr, nullptr);
    CONV(24,24,5,true ,false,3)(OA2, sum+4*64, sq+4*64, oa2_g, oa2_b,
        w_o3, oa3_bias, out, nullptr, nullptr, FUS, gk, aff_scale);
    #undef CONV
}

// Round 6
// 1406.024 us; speedup vs baseline: 1.5817x; 1.3499x over previous
//
#include <hip/hip_runtime.h>
#include <hip/hip_bf16.h>
#include <math.h>

#define B_   8
#define H_   320
#define W_   320
#define HW_  (320*320)

typedef __attribute__((ext_vector_type(8))) short bf16x8;
typedef __attribute__((ext_vector_type(4))) float f32x4;

__device__ __forceinline__ short f2b(float v){
    __hip_bfloat16 h = __float2bfloat16(v);
    return *(short*)&h;
}

// ---------------------------------------------------------------------------
// Repack ALL conv weights into MFMA A-fragment layout (bf16):
//   wr[((chunk*MT + mt)*16 + co_l)*32 + kl]  = W[co = mt*16+co_l][k = chunk*32+kl]
// K-order: k = tap*CIp + ci  (ci fastest). CIp=32: chunk=1 tap; CIp=8: 4 taps.
// Zero-padded for co>=COUT, ci>=CIN, tap>=K*K (fake taps).
// Segments (short offsets): f1 0, f2 9216, g1 13824, g2 39424, g3 52224,
//                           oa1 55808, oa2 59392, oa3 66560; total 92160.
// ---------------------------------------------------------------------------
__global__ void repack_k(const float* __restrict__ sf1, const float* __restrict__ sf2,
                         const float* __restrict__ sg1, const float* __restrict__ sg2,
                         const float* __restrict__ sg3, const float* __restrict__ so1,
                         const float* __restrict__ so2, const float* __restrict__ so3,
                         short* __restrict__ dst){
    const int cum[8]  = {9216,13824,39424,52224,55808,59392,66560,92160};
    const int CINs[8] = {32,32,32,32, 8, 8, 8,24};
    const int CIps[8] = {32,32,32,32, 8, 8, 8,32};
    const int COUTs[8]= {32, 1,32, 8, 8, 8,24,24};
    const int MTs[8]  = { 2, 1, 2, 1, 1, 1, 2, 2};
    const int Ks[8]   = { 3, 3, 5, 5, 5, 5, 5, 5};
    int i = blockIdx.x*256 + threadIdx.x;
    if (i >= 92160) return;
    int s = 0;
    while (i >= cum[s]) ++s;
    const int base = s ? cum[s-1] : 0;
    const int il = i - base;
    const float* src = (s==0)?sf1:(s==1)?sf2:(s==2)?sg1:(s==3)?sg2:(s==4)?sg3:(s==5)?so1:(s==6)?so2:so3;
    const int kl   = il & 31;
    const int co_l = (il >> 5) & 15;
    const int rem  = il >> 9;
    const int MT = MTs[s];
    const int mt = rem % MT;
    const int c  = rem / MT;
    int tap, ci;
    if (CIps[s] == 32){ tap = c; ci = kl; }
    else              { tap = c*4 + (kl>>3); ci = kl & 7; }
    const int K = Ks[s];
    const int co = mt*16 + co_l;
    float v = 0.f;
    if (co < COUTs[s] && ci < CINs[s] && tap < K*K){
        const int ky = tap / K, kx = tap - ky*K;
        v = src[((co*CINs[s] + ci)*K + ky)*K + kx];
    }
    dst[i] = f2b(v);
}

// ---------------------------------------------------------------------------
// Deform epilogue: given pixel's 24 oa3 values (+bias), deformable 3x3 gauss
// filter of fusion, return |.|   (verified r2-r5)
// ---------------------------------------------------------------------------
__device__ __forceinline__
float deform_px(const float* val, const float* __restrict__ fus_b,
                const float* __restrict__ gk_b, float inv_s, int y, int x){
    float aff[8]; float sa = 0.f;
    #pragma unroll
    for (int n=0;n<8;++n){
        float a = tanhf(val[16+n]) * inv_s + gk_b[n];
        aff[n] = a; sa += fabsf(a);
    }
    sa += 1e-5f;
    sa = fmaxf(sa, 1.f);
    const float isa = 1.f/sa;
    float ssum = 0.f;
    #pragma unroll
    for (int n=0;n<8;++n){ aff[n] *= isa; ssum += aff[n]; }
    const float aff_ref = 1.f - ssum;

    float o = 0.f;
    #pragma unroll
    for (int k=0;k<9;++k){
        float dy, dx, m;
        if (k == 4){ dy = 0.f; dx = 0.f; m = aff_ref; }
        else {
            const int n = (k < 4) ? k : k-1;
            dy = val[2*n];
            dx = val[2*n+1];
            m  = aff[n];
        }
        float yy = (float)(y + k/3 - 1) + dy;
        float xx = (float)(x + k%3 - 1) + dx;
        float y0f = floorf(yy), x0f = floorf(xx);
        int   y0 = (int)y0f,    x0i = (int)x0f;
        float wy1 = yy - y0f, wy0 = 1.f - wy1;
        float wx1 = xx - x0f, wx0 = 1.f - wx1;
        float v00 = (y0  >=0 && y0  <H_ && x0i  >=0 && x0i  <W_) ? fus_b[ y0   *W_ + x0i  ] : 0.f;
        float v01 = (y0  >=0 && y0  <H_ && x0i+1>=0 && x0i+1<W_) ? fus_b[ y0   *W_ + x0i+1] : 0.f;
        float v10 = (y0+1>=0 && y0+1<H_ && x0i  >=0 && x0i  <W_) ? fus_b[(y0+1)*W_ + x0i  ] : 0.f;
        float v11 = (y0+1>=0 && y0+1<H_ && x0i+1>=0 && x0i+1<W_) ? fus_b[(y0+1)*W_ + x0i+1] : 0.f;
        o += m * (wy0*(wx0*v00 + wx1*v01) + wy1*(wx0*v10 + wx1*v11));
    }
    return fabsf(o);
}

// ---------------------------------------------------------------------------
// MFMA implicit-GEMM conv.  D[co][px] = sum_k W[co][k] * im2col[k][px]
// Block: 256 thr = 4 waves; tile 32(x) x 4(y) px; wave w owns row y0+w,
// 2 N-tiles of 16 px.  A (weights, M=co) from global (L2), prefetch 1 chunk.
// B (pixels) from LDS (whole CIN staged as bf16 once -> ONE barrier pair).
// mfma_f32_16x16x32_bf16: A[m=lane&15][k=quad*8+j]; B[k=quad*8+j][n=lane&15];
// D[m=quad*4+reg][n=lane&15]  (m89/m91-verified layouts).
// CIp=32: chunk = 1 tap x 32ci.  CIp=8: chunk = 4 taps x 8ci (fake taps
// clamped to tap 0; their weights are zero).
// OUT_MODE: 0 raw, 1 +bias, 2 tanh(+bias), 3 deform epilogue (+bias).
// ---------------------------------------------------------------------------
template<int CIN, int CIp, int COUT, int MT, int K, bool IN_BN, bool OUT_STATS, int OUT_MODE>
__global__ __launch_bounds__(256, 4)
void mconv_k(const float* __restrict__ in,
             const float* __restrict__ bn_sum, const float* __restrict__ bn_sq,
             const float* __restrict__ gamma, const float* __restrict__ beta,
             const short* __restrict__ wr, const float* __restrict__ bias,
             float* __restrict__ out,
             float* __restrict__ osum, float* __restrict__ osq,
             const float* __restrict__ fus, const float* __restrict__ gk,
             const float* __restrict__ aff_scale){
    constexpr int PAD = K/2;
    constexpr int LW  = 32 + K - 1;
    constexpr int LH  = 4 + K - 1;
    constexpr int NTAPS  = K*K;
    constexpr int NCHUNK = (CIp==32) ? NTAPS : (NTAPS*CIp + 31)/32;
    constexpr int INB  = LH*LW*CIp*2;
    constexpr int LDSB = (OUT_MODE==3 && INB < 128*32*4) ? 128*32*4 : INB;

    __shared__ __align__(16) char ldsraw[LDSB];
    short* lds_in = (short*)ldsraw;
    __shared__ float sc_sh[2][32];
    __shared__ float red[2][4][32];

    const int tid = threadIdx.x;
    const int b   = blockIdx.z;
    const int x0  = blockIdx.x*32, y0 = blockIdx.y*4;

    if (IN_BN){
        if (tid < CIN){
            const float invN = 1.f/(float)(B_*HW_);
            float mu  = bn_sum[tid]*invN;
            float var = bn_sq[tid]*invN - mu*mu;
            float s = gamma[tid] * rsqrtf(var + 1e-5f);
            sc_sh[0][tid] = s;
            sc_sh[1][tid] = beta[tid] - mu*s;
        }
        __syncthreads();
    }

    // ---- stage whole CIN depth as bf16: lds_in[y][x][CIp] ----
    {
        const int sx = tid & 31;
        const int ss = tid >> 5;                  // 8 channel slots
        for (int r = 0; r < LH; ++r){
            const int gy = y0 + r - PAD;
            const bool rok = (gy>=0) & (gy<H_);
            for (int ci = ss; ci < CIp; ci += 8){
                float sc = 1.f, sh = 0.f;
                if (IN_BN && ci < CIN){ sc = sc_sh[0][ci]; sh = sc_sh[1][ci]; }
                const float* src = in + ((long)b*CIN + ci)*HW_ + gy*W_;
                #pragma unroll
                for (int h=0; h<2; ++h){
                    const int xl = sx + h*32;
                    if (xl < LW){
                        const int gx = x0 + xl - PAD;
                        float v = 0.f;
                        if (ci < CIN && rok && gx>=0 && gx<W_){
                            v = src[gx];
                            if (IN_BN) v = fmaxf(fmaf(v, sc, sh), 0.f);
                        }
                        lds_in[(r*LW + xl)*CIp + ci] = f2b(v);
                    }
                }
            }
        }
    }
    __syncthreads();

    const int lane = tid & 63;
    const int wv   = tid >> 6;                    // wave = y-row
    const int pxn  = lane & 15;
    const int quad = lane >> 4;

    const f32x4 zero = {0.f, 0.f, 0.f, 0.f};
    f32x4 acc[MT][2];
    #pragma unroll
    for (int m=0;m<MT;++m){ acc[m][0] = zero; acc[m][1] = zero; }

    bf16x8 acur[MT], anxt[MT];
    #pragma unroll
    for (int m=0;m<MT;++m){
        acur[m] = *(const bf16x8*)(wr + (((0*MT + m)*16 + pxn)*32 + quad*8));
        anxt[m] = acur[m];
    }

    for (int c=0; c<NCHUNK; ++c){
        if (c+1 < NCHUNK){
            #pragma unroll
            for (int m=0;m<MT;++m)
                anxt[m] = *(const bf16x8*)(wr + ((((c+1)*MT + m)*16 + pxn)*32 + quad*8));
        }
        const short* bp;
        if (CIp == 32){
            const int ky = c / K, kx = c - ky*K;
            bp = lds_in + ((wv+ky)*LW + kx + pxn)*CIp + quad*8;
        } else {
            int t = c*4 + quad;
            if (t >= NTAPS) t = 0;                // fake tap (zero weights)
            const int ky = t / K, kx = t - ky*K;
            bp = lds_in + ((wv+ky)*LW + kx + pxn)*CIp;
        }
        const bf16x8 b0 = *(const bf16x8*)bp;
        const bf16x8 b1 = *(const bf16x8*)(bp + 16*CIp);
        #pragma unroll
        for (int m=0;m<MT;++m){
            acc[m][0] = __builtin_amdgcn_mfma_f32_16x16x32_bf16(acur[m], b0, acc[m][0], 0,0,0);
            acc[m][1] = __builtin_amdgcn_mfma_f32_16x16x32_bf16(acur[m], b1, acc[m][1], 0,0,0);
        }
        #pragma unroll
        for (int m=0;m<MT;++m) acur[m] = anxt[m];
    }

    // ---- fused BN-stats epilogue (raw pre-bias acc) ----
    if (OUT_STATS){
        #pragma unroll
        for (int m=0;m<MT;++m){
            #pragma unroll
            for (int r=0;r<4;++r){
                float v  = acc[m][0][r] + acc[m][1][r];
                float v2 = acc[m][0][r]*acc[m][0][r] + acc[m][1][r]*acc[m][1][r];
                #pragma unroll
                for (int o=1;o<16;o<<=1){
                    v  += __shfl_xor(v,  o, 64);
                    v2 += __shfl_xor(v2, o, 64);
                }
                if (pxn == 0){
                    red[0][wv][m*16 + quad*4 + r] = v;
                    red[1][wv][m*16 + quad*4 + r] = v2;
                }
            }
        }
        __syncthreads();
        if (tid < MT*16 && tid < COUT){
            atomicAdd(&osum[tid], red[0][0][tid]+red[0][1][tid]+red[0][2][tid]+red[0][3][tid]);
            atomicAdd(&osq[tid],  red[1][0][tid]+red[1][1][tid]+red[1][2][tid]+red[1][3][tid]);
        }
    }

    const int y = y0 + wv;
    if (OUT_MODE == 3){
        // gather per-pixel co-vector via LDS, then deform
        __syncthreads();                          // done reading lds_in
        float* dumpf = (float*)ldsraw;
        #pragma unroll
        for (int m=0;m<MT;++m)
            #pragma unroll
            for (int n=0;n<2;++n)
                #pragma unroll
                for (int r=0;r<4;++r)
                    dumpf[(wv*32 + n*16 + pxn)*32 + (m*16 + quad*4 + r)] = acc[m][n][r];
        __syncthreads();
        if (tid < 128){
            float val[24];
            #pragma unroll
            for (int c2=0;c2<24;++c2) val[c2] = dumpf[tid*32 + c2] + bias[c2];
            const int yy = y0 + (tid>>5), xx = x0 + (tid&31);
            const float inv_s = 1.f/(aff_scale[0] + 1e-5f);
            out[(long)b*HW_ + yy*W_ + xx] =
                deform_px(val, fus + (long)b*HW_, gk + b*8, inv_s, yy, xx);
        }
    } else {
        #pragma unroll
        for (int m=0;m<MT;++m){
            #pragma unroll
            for (int r=0;r<4;++r){
                const int co = m*16 + quad*4 + r;
                if (co < COUT){
                    float* op = out + (((long)b*COUT + co)*H_ + y)*W_ + x0;
                    #pragma unroll
                    for (int n=0;n<2;++n){
                        float o = acc[m][n][r];
                        if (OUT_MODE >= 1) o += bias[co];
                        if (OUT_MODE == 2) o = tanhf(o);
                        op[n*16 + pxn] = o;
                    }
                }
            }
        }
    }
}

// ---------------------------------------------------------------------------
// Global average pool of feat -> p (B,32). One block per (b,c).
// ---------------------------------------------------------------------------
__global__ void pool_k(const float* __restrict__ feat, float* __restrict__ p){
    const int bc = blockIdx.x;
    const float* src = feat + (long)bc*HW_;
    float s = 0.f;
    for (int i=threadIdx.x; i<HW_; i+=256) s += src[i];
    #pragma unroll
    for (int off=32; off; off>>=1) s += __shfl_down(s, off, 64);
    __shared__ float red[4];
    const int lane = threadIdx.x & 63, wid = threadIdx.x >> 6;
    if (lane == 0) red[wid] = s;
    __syncthreads();
    if (threadIdx.x == 0)
        p[bc] = (red[0]+red[1]+red[2]+red[3]) * (1.f/(float)HW_);
}

// ---------------------------------------------------------------------------
// CAM MLP (32->16 celu ->16 celu ->1 relu +0.001) then gauss_win -> gk (B,8)
// ---------------------------------------------------------------------------
__global__ void sigma_k(const float* __restrict__ p,
                        const float* s1w, const float* s1b,
                        const float* s2w, const float* s2b,
                        const float* s3w, const float* s3b,
                        float* __restrict__ gk){
    const int b = threadIdx.x;
    if (b >= B_) return;
    float h1[16], h2[16];
    for (int i=0;i<16;++i){
        float t = s1b[i];
        for (int j=0;j<32;++j) t = fmaf(p[b*32+j], s1w[i*32+j], t);
        h1[i] = t > 0.f ? t : expm1f(t);          // celu(alpha=1)
    }
    for (int i=0;i<16;++i){
        float t = s2b[i];
        for (int j=0;j<16;++j) t = fmaf(h1[j], s2w[i*16+j], t);
        h2[i] = t > 0.f ? t : expm1f(t);
    }
    float t = s3b[0];
    for (int j=0;j<16;++j) t = fmaf(h2[j], s3w[j], t);
    float sigma = fmaxf(t, 0.f) + 0.001f;
    float sg = sigma + 0.2f;                      // sigma_gamma = 0.2
    float e = expf(-1.f/(2.f*sg*sg));
    float inv = 1.f/(2.f*e + 1.f);
    float a = e*inv, c = inv;                     // w1 = [a, c, a]
    float* g = gk + b*8;                          // outer(w1,w1) flat minus center
    g[0]=a*a; g[1]=a*c; g[2]=a*a; g[3]=c*a; g[4]=c*a; g[5]=a*a; g[6]=a*c; g[7]=a*a;
}

// ---------------------------------------------------------------------------
extern "C" void kernel_launch(void* const* d_in, const int* in_sizes, int n_in,
                              void* d_out, int out_size, void* d_ws, size_t ws_size,
                              hipStream_t stream){
    const float* feat    = (const float*)d_in[0];
    const float* g1_w    = (const float*)d_in[1];
    const float* g1_g    = (const float*)d_in[2];
    const float* g1_b    = (const float*)d_in[3];
    const float* g2_w    = (const float*)d_in[4];
    const float* g2_g    = (const float*)d_in[5];
    const float* g2_b    = (const float*)d_in[6];
    const float* g3_w    = (const float*)d_in[7];
    const float* g3_bias = (const float*)d_in[8];
    const float* f1_w    = (const float*)d_in[9];
    const float* f1_g    = (const float*)d_in[10];
    const float* f1_b    = (const float*)d_in[11];
    const float* f2_w    = (const float*)d_in[12];
    const float* f2_bias = (const float*)d_in[13];
    const float* s1w     = (const float*)d_in[14];
    const float* s1b     = (const float*)d_in[15];
    const float* s2w     = (const float*)d_in[16];
    const float* s2b     = (const float*)d_in[17];
    const float* s3w     = (const float*)d_in[18];
    const float* s3b     = (const float*)d_in[19];
    const float* oa1_w   = (const float*)d_in[20];
    const float* oa1_g   = (const float*)d_in[21];
    const float* oa1_b   = (const float*)d_in[22];
    const float* oa2_w   = (const float*)d_in[23];
    const float* oa2_g   = (const float*)d_in[24];
    const float* oa2_b   = (const float*)d_in[25];
    const float* oa3_w   = (const float*)d_in[26];
    const float* oa3_bias= (const float*)d_in[27];
    const float* aff_scale=(const float*)d_in[28];
    float* out = (float*)d_out;

    // workspace (fp32 intermediates, unchanged from r5):
    char* ws = (char*)d_ws;
    float* A1   = (float*)(ws + 0L);            // 32ch, aliased by OA2 later
    float* A2   = (float*)(ws + 104857600L);    // 8ch
    float* GUID = (float*)(ws + 131072000L);    // 8ch
    float* FUS  = (float*)(ws + 157286400L);    // 1ch
    float* SM   = (float*)(ws + 160563200L);    // stats + p + gk + weights
    float* OA2  = A1;

    float* sum = SM;             // 5 slots x 64
    float* sq  = SM + 320;
    float* p   = SM + 640;       // 256
    float* gk  = SM + 896;       // 64
    short* WBs = (short*)(SM + 960);   // bf16 MFMA weights, 92160 shorts
    short* w_f1 = WBs + 0;
    short* w_f2 = WBs + 9216;
    short* w_g1 = WBs + 13824;
    short* w_g2 = WBs + 39424;
    short* w_g3 = WBs + 52224;
    short* w_o1 = WBs + 55808;
    short* w_o2 = WBs + 59392;
    short* w_o3 = WBs + 66560;

    hipMemsetAsync(sum, 0, 640*sizeof(float), stream);   // zero sum+sumsq

    repack_k<<<dim3(360), dim3(256), 0, stream>>>(
        f1_w, f2_w, g1_w, g2_w, g3_w, oa1_w, oa2_w, oa3_w, WBs);

    // sigma branch (independent)
    pool_k<<<dim3(256), dim3(256), 0, stream>>>(feat, p);
    sigma_k<<<dim3(1), dim3(64), 0, stream>>>(p, s1w, s1b, s2w, s2b, s3w, s3b, gk);

    const dim3 cgrid(10, 80, 8), cblk(256);
    #define MCONV(CIN,CIp,COUT,MT,K,IBN,OST,OM) \
        mconv_k<CIN,CIp,COUT,MT,K,IBN,OST,OM><<<cgrid,cblk,0,stream>>>

    // fuse branch: f1 (3x3 32->32, stats) -> f2 (bn in, 3x3 32->1, tanh)
    MCONV(32,32,32,2,3,false,true ,0)(feat, nullptr, nullptr, nullptr, nullptr,
        w_f1, nullptr, A1, sum+0*64, sq+0*64, nullptr, nullptr, nullptr);
    MCONV(32,32, 1,1,3,true ,false,2)(A1, sum+0*64, sq+0*64, f1_g, f1_b,
        w_f2, f2_bias, FUS, nullptr, nullptr, nullptr, nullptr, nullptr);

    // guid branch: g1 (5x5 32->32, stats) -> g2 (5x5 32->8, stats) -> g3 (5x5 8->8 +bias)
    MCONV(32,32,32,2,5,false,true ,0)(feat, nullptr, nullptr, nullptr, nullptr,
        w_g1, nullptr, A1, sum+1*64, sq+1*64, nullptr, nullptr, nullptr);
    MCONV(32,32, 8,1,5,true ,true ,0)(A1, sum+1*64, sq+1*64, g1_g, g1_b,
        w_g2, nullptr, A2, sum+2*64, sq+2*64, nullptr, nullptr, nullptr);
    MCONV( 8, 8, 8,1,5,true ,false,1)(A2, sum+2*64, sq+2*64, g2_g, g2_b,
        w_g3, g3_bias, GUID, nullptr, nullptr, nullptr, nullptr, nullptr);

    // off_aff branch: oa1 (5x5 8->8, stats) -> oa2 (5x5 8->24, stats)
    //                 -> oa3 (5x5 24->24 +bias) fused with deform -> out
    MCONV( 8, 8, 8,1,5,false,true ,0)(GUID, nullptr, nullptr, nullptr, nullptr,
        w_o1, nullptr, A2, sum+3*64, sq+3*64, nullptr, nullptr, nullptr);
    MCONV( 8, 8,24,2,5,true ,true ,0)(A2, sum+3*64, sq+3*64, oa1_g, oa1_b,
        w_o2, nullptr, OA2, sum+4*64, sq+4*64, nullptr, nullptr, nullptr);
    MCONV(24,32,24,2,5,true ,false,3)(OA2, sum+4*64, sq+4*64, oa2_g, oa2_b,
        w_o3, oa3_bias, out, nullptr, nullptr, FUS, gk, aff_scale);
    #undef MCONV
}

// Round 7
// 1390.149 us; speedup vs baseline: 1.5997x; 1.0114x over previous
//
#include <hip/hip_runtime.h>
#include <hip/hip_bf16.h>
#include <math.h>

#define B_   8
#define H_   320
#define W_   320
#define HW_  (320*320)

typedef __attribute__((ext_vector_type(8))) short bf16x8;
typedef __attribute__((ext_vector_type(4))) float f32x4;

__device__ __forceinline__ short f2b(float v){
    __hip_bfloat16 h = __float2bfloat16(v);
    return *(short*)&h;
}

// ---------------------------------------------------------------------------
// Repack ALL conv weights into MFMA A-fragment layout (bf16):
//   wr[((chunk*MT + mt)*16 + co_l)*32 + kl]  = W[co = mt*16+co_l][k = chunk*32+kl]
// K-order: k = tap*CIp + ci  (ci fastest). CIp=32: chunk=1 tap; CIp=8: 4 taps.
// Zero-padded for co>=COUT, ci>=CIN, tap>=K*K (fake taps).
// ---------------------------------------------------------------------------
__global__ void repack_k(const float* __restrict__ sf1, const float* __restrict__ sf2,
                         const float* __restrict__ sg1, const float* __restrict__ sg2,
                         const float* __restrict__ sg3, const float* __restrict__ so1,
                         const float* __restrict__ so2, const float* __restrict__ so3,
                         short* __restrict__ dst){
    const int cum[8]  = {9216,13824,39424,52224,55808,59392,66560,92160};
    const int CINs[8] = {32,32,32,32, 8, 8, 8,24};
    const int CIps[8] = {32,32,32,32, 8, 8, 8,32};
    const int COUTs[8]= {32, 1,32, 8, 8, 8,24,24};
    const int MTs[8]  = { 2, 1, 2, 1, 1, 1, 2, 2};
    const int Ks[8]   = { 3, 3, 5, 5, 5, 5, 5, 5};
    int i = blockIdx.x*256 + threadIdx.x;
    if (i >= 92160) return;
    int s = 0;
    while (i >= cum[s]) ++s;
    const int base = s ? cum[s-1] : 0;
    const int il = i - base;
    const float* src = (s==0)?sf1:(s==1)?sf2:(s==2)?sg1:(s==3)?sg2:(s==4)?sg3:(s==5)?so1:(s==6)?so2:so3;
    const int kl   = il & 31;
    const int co_l = (il >> 5) & 15;
    const int rem  = il >> 9;
    const int MT = MTs[s];
    const int mt = rem % MT;
    const int c  = rem / MT;
    int tap, ci;
    if (CIps[s] == 32){ tap = c; ci = kl; }
    else              { tap = c*4 + (kl>>3); ci = kl & 7; }
    const int K = Ks[s];
    const int co = mt*16 + co_l;
    float v = 0.f;
    if (co < COUTs[s] && ci < CINs[s] && tap < K*K){
        const int ky = tap / K, kx = tap - ky*K;
        v = src[((co*CINs[s] + ci)*K + ky)*K + kx];
    }
    dst[i] = f2b(v);
}

// ---------------------------------------------------------------------------
// Deform epilogue: given pixel's 24 oa3 values (+bias), deformable 3x3 gauss
// filter of fusion, return |.|   (verified r2-r6)
// ---------------------------------------------------------------------------
__device__ __forceinline__
float deform_px(const float* val, const float* __restrict__ fus_b,
                const float* __restrict__ gk_b, float inv_s, int y, int x){
    float aff[8]; float sa = 0.f;
    #pragma unroll
    for (int n=0;n<8;++n){
        float a = tanhf(val[16+n]) * inv_s + gk_b[n];
        aff[n] = a; sa += fabsf(a);
    }
    sa += 1e-5f;
    sa = fmaxf(sa, 1.f);
    const float isa = 1.f/sa;
    float ssum = 0.f;
    #pragma unroll
    for (int n=0;n<8;++n){ aff[n] *= isa; ssum += aff[n]; }
    const float aff_ref = 1.f - ssum;

    float o = 0.f;
    #pragma unroll
    for (int k=0;k<9;++k){
        float dy, dx, m;
        if (k == 4){ dy = 0.f; dx = 0.f; m = aff_ref; }
        else {
            const int n = (k < 4) ? k : k-1;
            dy = val[2*n];
            dx = val[2*n+1];
            m  = aff[n];
        }
        float yy = (float)(y + k/3 - 1) + dy;
        float xx = (float)(x + k%3 - 1) + dx;
        float y0f = floorf(yy), x0f = floorf(xx);
        int   y0 = (int)y0f,    x0i = (int)x0f;
        float wy1 = yy - y0f, wy0 = 1.f - wy1;
        float wx1 = xx - x0f, wx0 = 1.f - wx1;
        float v00 = (y0  >=0 && y0  <H_ && x0i  >=0 && x0i  <W_) ? fus_b[ y0   *W_ + x0i  ] : 0.f;
        float v01 = (y0  >=0 && y0  <H_ && x0i+1>=0 && x0i+1<W_) ? fus_b[ y0   *W_ + x0i+1] : 0.f;
        float v10 = (y0+1>=0 && y0+1<H_ && x0i  >=0 && x0i  <W_) ? fus_b[(y0+1)*W_ + x0i  ] : 0.f;
        float v11 = (y0+1>=0 && y0+1<H_ && x0i+1>=0 && x0i+1<W_) ? fus_b[(y0+1)*W_ + x0i+1] : 0.f;
        o += m * (wy0*(wx0*v00 + wx1*v01) + wy1*(wx0*v10 + wx1*v11));
    }
    return fabsf(o);
}

// ---------------------------------------------------------------------------
// MFMA implicit-GEMM conv.  D[co][px] = sum_k W[co][k] * im2col[k][px]
// Block: 256 thr = 4 waves; tile 32(x) x 4(y); wave w owns row y0+w, 2 N-tiles.
// A (weights) global/L2, prefetch 1 chunk.  B (pixels) LDS, prefetch 1 chunk.
// LDS layout lds_in[y][x][STR]: STR=40 for CIp=32 (80B=20 banks -> 2-way,
// free; the unpadded 64B stride was 8-way = 3.1e7 conflicts in r6).
// mfma_f32_16x16x32_bf16 layouts per m89/m91.
// ---------------------------------------------------------------------------
template<int CIN, int CIp, int COUT, int MT, int K, bool IN_BN, bool OUT_STATS, int OUT_MODE>
__global__ __launch_bounds__(256, 4)
void mconv_k(const float* __restrict__ in,
             const float* __restrict__ bn_sum, const float* __restrict__ bn_sq,
             const float* __restrict__ gamma, const float* __restrict__ beta,
             const short* __restrict__ wr, const float* __restrict__ bias,
             float* __restrict__ out,
             float* __restrict__ osum, float* __restrict__ osq,
             const float* __restrict__ fus, const float* __restrict__ gk,
             const float* __restrict__ aff_scale){
    constexpr int PAD = K/2;
    constexpr int LW  = 32 + K - 1;
    constexpr int LH  = 4 + K - 1;
    constexpr int STR = (CIp==32) ? 40 : 8;     // bank-conflict pad
    constexpr int NTAPS  = K*K;
    constexpr int NCHUNK = (CIp==32) ? NTAPS : (NTAPS*CIp + 31)/32;
    constexpr int INB  = LH*LW*STR*2;
    constexpr int DUMPB = 128*33*4;             // deform dump, stride 33 (no conflict)
    constexpr int LDSB = (OUT_MODE==3 && INB < DUMPB) ? DUMPB : INB;

    __shared__ __align__(16) char ldsraw[LDSB];
    short* lds_in = (short*)ldsraw;
    __shared__ float sc_sh[2][32];
    __shared__ float red[2][4][32];

    const int tid = threadIdx.x;
    const int b   = blockIdx.z;
    const int x0  = blockIdx.x*32, y0 = blockIdx.y*4;

    if (IN_BN){
        if (tid < CIN){
            const float invN = 1.f/(float)(B_*HW_);
            float mu  = bn_sum[tid]*invN;
            float var = bn_sq[tid]*invN - mu*mu;
            float s = gamma[tid] * rsqrtf(var + 1e-5f);
            sc_sh[0][tid] = s;
            sc_sh[1][tid] = beta[tid] - mu*s;
        }
        __syncthreads();
    }

    // ---- stage whole CIN depth as bf16, pair-packed ds_write_b32 ----
    {
        const int sx = tid & 31;
        const int ss = tid >> 5;                  // 8 slots over ci-pairs
        constexpr int NPAIR = CIp/2;
        for (int r = 0; r < LH; ++r){
            const int gy = y0 + r - PAD;
            const bool rok = (gy>=0) & (gy<H_);
            for (int pp = ss; pp < NPAIR; pp += 8){
                const int c0i = 2*pp, c1i = 2*pp+1;
                float sc0=1.f, sh0=0.f, sc1=1.f, sh1=0.f;
                if (IN_BN){
                    if (c0i < CIN){ sc0 = sc_sh[0][c0i]; sh0 = sc_sh[1][c0i]; }
                    if (c1i < CIN){ sc1 = sc_sh[0][c1i]; sh1 = sc_sh[1][c1i]; }
                }
                const float* s0 = in + ((long)b*CIN + c0i)*HW_ + gy*W_;
                const float* s1 = in + ((long)b*CIN + c1i)*HW_ + gy*W_;
                #pragma unroll
                for (int h=0; h<2; ++h){
                    const int xl = sx + h*32;
                    if (xl < LW){
                        const int gx = x0 + xl - PAD;
                        float v0 = 0.f, v1 = 0.f;
                        if (rok && gx>=0 && gx<W_){
                            if (c0i < CIN){
                                v0 = s0[gx];
                                if (IN_BN) v0 = fmaxf(fmaf(v0, sc0, sh0), 0.f);
                            }
                            if (c1i < CIN){
                                v1 = s1[gx];
                                if (IN_BN) v1 = fmaxf(fmaf(v1, sc1, sh1), 0.f);
                            }
                        }
                        unsigned u = (unsigned)(unsigned short)f2b(v0)
                                   | ((unsigned)(unsigned short)f2b(v1) << 16);
                        *(unsigned*)&lds_in[(r*LW + xl)*STR + c0i] = u;
                    }
                }
            }
        }
    }
    __syncthreads();

    const int lane = tid & 63;
    const int wv   = tid >> 6;                    // wave = y-row
    const int pxn  = lane & 15;
    const int quad = lane >> 4;

    const f32x4 zero = {0.f, 0.f, 0.f, 0.f};
    f32x4 acc[MT][2];
    #pragma unroll
    for (int m=0;m<MT;++m){ acc[m][0] = zero; acc[m][1] = zero; }

    auto bptr = [&](int c)->const short*{
        if (CIp == 32){
            const int ky = c / K, kx = c - ky*K;
            return lds_in + ((wv+ky)*LW + kx + pxn)*STR + quad*8;
        } else {
            int t = c*4 + quad;
            if (t >= NTAPS) t = 0;                // fake tap (zero weights)
            const int ky = t / K, kx = t - ky*K;
            return lds_in + ((wv+ky)*LW + kx + pxn)*STR;
        }
    };

    bf16x8 acur[MT], anxt[MT];
    #pragma unroll
    for (int m=0;m<MT;++m)
        acur[m] = *(const bf16x8*)(wr + ((m*16 + pxn)*32 + quad*8));
    const short* bp0 = bptr(0);
    bf16x8 b0c = *(const bf16x8*)bp0;
    bf16x8 b1c = *(const bf16x8*)(bp0 + 16*STR);

    for (int c=0; c<NCHUNK; ++c){
        bf16x8 b0n = b0c, b1n = b1c;
        if (c+1 < NCHUNK){
            #pragma unroll
            for (int m=0;m<MT;++m)
                anxt[m] = *(const bf16x8*)(wr + ((((c+1)*MT + m)*16 + pxn)*32 + quad*8));
            const short* bpn = bptr(c+1);
            b0n = *(const bf16x8*)bpn;
            b1n = *(const bf16x8*)(bpn + 16*STR);
        }
        #pragma unroll
        for (int m=0;m<MT;++m){
            acc[m][0] = __builtin_amdgcn_mfma_f32_16x16x32_bf16(acur[m], b0c, acc[m][0], 0,0,0);
            acc[m][1] = __builtin_amdgcn_mfma_f32_16x16x32_bf16(acur[m], b1c, acc[m][1], 0,0,0);
        }
        #pragma unroll
        for (int m=0;m<MT;++m) acur[m] = anxt[m];
        b0c = b0n; b1c = b1n;
    }

    // ---- fused BN-stats epilogue (raw pre-bias acc) ----
    if (OUT_STATS){
        #pragma unroll
        for (int m=0;m<MT;++m){
            #pragma unroll
            for (int r=0;r<4;++r){
                float v  = acc[m][0][r] + acc[m][1][r];
                float v2 = acc[m][0][r]*acc[m][0][r] + acc[m][1][r]*acc[m][1][r];
                #pragma unroll
                for (int o=1;o<16;o<<=1){
                    v  += __shfl_xor(v,  o, 64);
                    v2 += __shfl_xor(v2, o, 64);
                }
                if (pxn == 0){
                    red[0][wv][m*16 + quad*4 + r] = v;
                    red[1][wv][m*16 + quad*4 + r] = v2;
                }
            }
        }
        __syncthreads();
        if (tid < MT*16 && tid < COUT){
            atomicAdd(&osum[tid], red[0][0][tid]+red[0][1][tid]+red[0][2][tid]+red[0][3][tid]);
            atomicAdd(&osq[tid],  red[1][0][tid]+red[1][1][tid]+red[1][2][tid]+red[1][3][tid]);
        }
    }

    const int y = y0 + wv;
    if (OUT_MODE == 3){
        // gather per-pixel co-vector via LDS (stride 33: conflict-free), deform
        __syncthreads();                          // done reading lds_in
        float* dumpf = (float*)ldsraw;
        #pragma unroll
        for (int m=0;m<MT;++m)
            #pragma unroll
            for (int n=0;n<2;++n)
                #pragma unroll
                for (int r=0;r<4;++r)
                    dumpf[(wv*32 + n*16 + pxn)*33 + (m*16 + quad*4 + r)] = acc[m][n][r];
        __syncthreads();
        if (tid < 128){
            float val[24];
            #pragma unroll
            for (int c2=0;c2<24;++c2) val[c2] = dumpf[tid*33 + c2] + bias[c2];
            const int yy = y0 + (tid>>5), xx = x0 + (tid&31);
            const float inv_s = 1.f/(aff_scale[0] + 1e-5f);
            out[(long)b*HW_ + yy*W_ + xx] =
                deform_px(val, fus + (long)b*HW_, gk + b*8, inv_s, yy, xx);
        }
    } else {
        #pragma unroll
        for (int m=0;m<MT;++m){
            #pragma unroll
            for (int r=0;r<4;++r){
                const int co = m*16 + quad*4 + r;
                if (co < COUT){
                    float* op = out + (((long)b*COUT + co)*H_ + y)*W_ + x0;
                    #pragma unroll
                    for (int n=0;n<2;++n){
                        float o = acc[m][n][r];
                        if (OUT_MODE >= 1) o += bias[co];
                        if (OUT_MODE == 2) o = tanhf(o);
                        op[n*16 + pxn] = o;
                    }
                }
            }
        }
    }
}

// ---------------------------------------------------------------------------
// Global average pool of feat -> p (B,32). One block per (b,c).
// ---------------------------------------------------------------------------
__global__ void pool_k(const float* __restrict__ feat, float* __restrict__ p){
    const int bc = blockIdx.x;
    const float* src = feat + (long)bc*HW_;
    float s = 0.f;
    for (int i=threadIdx.x; i<HW_; i+=256) s += src[i];
    #pragma unroll
    for (int off=32; off; off>>=1) s += __shfl_down(s, off, 64);
    __shared__ float red[4];
    const int lane = threadIdx.x & 63, wid = threadIdx.x >> 6;
    if (lane == 0) red[wid] = s;
    __syncthreads();
    if (threadIdx.x == 0)
        p[bc] = (red[0]+red[1]+red[2]+red[3]) * (1.f/(float)HW_);
}

// ---------------------------------------------------------------------------
// CAM MLP (32->16 celu ->16 celu ->1 relu +0.001) then gauss_win -> gk (B,8)
// ---------------------------------------------------------------------------
__global__ void sigma_k(const float* __restrict__ p,
                        const float* s1w, const float* s1b,
                        const float* s2w, const float* s2b,
                        const float* s3w, const float* s3b,
                        float* __restrict__ gk){
    const int b = threadIdx.x;
    if (b >= B_) return;
    float h1[16], h2[16];
    for (int i=0;i<16;++i){
        float t = s1b[i];
        for (int j=0;j<32;++j) t = fmaf(p[b*32+j], s1w[i*32+j], t);
        h1[i] = t > 0.f ? t : expm1f(t);          // celu(alpha=1)
    }
    for (int i=0;i<16;++i){
        float t = s2b[i];
        for (int j=0;j<16;++j) t = fmaf(h1[j], s2w[i*16+j], t);
        h2[i] = t > 0.f ? t : expm1f(t);
    }
    float t = s3b[0];
    for (int j=0;j<16;++j) t = fmaf(h2[j], s3w[j], t);
    float sigma = fmaxf(t, 0.f) + 0.001f;
    float sg = sigma + 0.2f;                      // sigma_gamma = 0.2
    float e = expf(-1.f/(2.f*sg*sg));
    float inv = 1.f/(2.f*e + 1.f);
    float a = e*inv, c = inv;                     // w1 = [a, c, a]
    float* g = gk + b*8;                          // outer(w1,w1) flat minus center
    g[0]=a*a; g[1]=a*c; g[2]=a*a; g[3]=c*a; g[4]=c*a; g[5]=a*a; g[6]=a*c; g[7]=a*a;
}

// ---------------------------------------------------------------------------
extern "C" void kernel_launch(void* const* d_in, const int* in_sizes, int n_in,
                              void* d_out, int out_size, void* d_ws, size_t ws_size,
                              hipStream_t stream){
    const float* feat    = (const float*)d_in[0];
    const float* g1_w    = (const float*)d_in[1];
    const float* g1_g    = (const float*)d_in[2];
    const float* g1_b    = (const float*)d_in[3];
    const float* g2_w    = (const float*)d_in[4];
    const float* g2_g    = (const float*)d_in[5];
    const float* g2_b    = (const float*)d_in[6];
    const float* g3_w    = (const float*)d_in[7];
    const float* g3_bias = (const float*)d_in[8];
    const float* f1_w    = (const float*)d_in[9];
    const float* f1_g    = (const float*)d_in[10];
    const float* f1_b    = (const float*)d_in[11];
    const float* f2_w    = (const float*)d_in[12];
    const float* f2_bias = (const float*)d_in[13];
    const float* s1w     = (const float*)d_in[14];
    const float* s1b     = (const float*)d_in[15];
    const float* s2w     = (const float*)d_in[16];
    const float* s2b     = (const float*)d_in[17];
    const float* s3w     = (const float*)d_in[18];
    const float* s3b     = (const float*)d_in[19];
    const float* oa1_w   = (const float*)d_in[20];
    const float* oa1_g   = (const float*)d_in[21];
    const float* oa1_b   = (const float*)d_in[22];
    const float* oa2_w   = (const float*)d_in[23];
    const float* oa2_g   = (const float*)d_in[24];
    const float* oa2_b   = (const float*)d_in[25];
    const float* oa3_w   = (const float*)d_in[26];
    const float* oa3_bias= (const float*)d_in[27];
    const float* aff_scale=(const float*)d_in[28];
    float* out = (float*)d_out;

    // workspace (fp32 intermediates):
    char* ws = (char*)d_ws;
    float* A1   = (float*)(ws + 0L);            // 32ch, aliased by OA2 later
    float* A2   = (float*)(ws + 104857600L);    // 8ch
    float* GUID = (float*)(ws + 131072000L);    // 8ch
    float* FUS  = (float*)(ws + 157286400L);    // 1ch
    float* SM   = (float*)(ws + 160563200L);    // stats + p + gk + weights
    float* OA2  = A1;

    float* sum = SM;             // 5 slots x 64
    float* sq  = SM + 320;
    float* p   = SM + 640;       // 256
    float* gk  = SM + 896;       // 64
    short* WBs = (short*)(SM + 960);   // bf16 MFMA weights, 92160 shorts
    short* w_f1 = WBs + 0;
    short* w_f2 = WBs + 9216;
    short* w_g1 = WBs + 13824;
    short* w_g2 = WBs + 39424;
    short* w_g3 = WBs + 52224;
    short* w_o1 = WBs + 55808;
    short* w_o2 = WBs + 59392;
    short* w_o3 = WBs + 66560;

    hipMemsetAsync(sum, 0, 640*sizeof(float), stream);   // zero sum+sumsq

    repack_k<<<dim3(360), dim3(256), 0, stream>>>(
        f1_w, f2_w, g1_w, g2_w, g3_w, oa1_w, oa2_w, oa3_w, WBs);

    // sigma branch (independent)
    pool_k<<<dim3(256), dim3(256), 0, stream>>>(feat, p);
    sigma_k<<<dim3(1), dim3(64), 0, stream>>>(p, s1w, s1b, s2w, s2b, s3w, s3b, gk);

    const dim3 cgrid(10, 80, 8), cblk(256);
    #define MCONV(CIN,CIp,COUT,MT,K,IBN,OST,OM) \
        mconv_k<CIN,CIp,COUT,MT,K,IBN,OST,OM><<<cgrid,cblk,0,stream>>>

    // fuse branch: f1 (3x3 32->32, stats) -> f2 (bn in, 3x3 32->1, tanh)
    MCONV(32,32,32,2,3,false,true ,0)(feat, nullptr, nullptr, nullptr, nullptr,
        w_f1, nullptr, A1, sum+0*64, sq+0*64, nullptr, nullptr, nullptr);
    MCONV(32,32, 1,1,3,true ,false,2)(A1, sum+0*64, sq+0*64, f1_g, f1_b,
        w_f2, f2_bias, FUS, nullptr, nullptr, nullptr, nullptr, nullptr);

    // guid branch: g1 (5x5 32->32, stats) -> g2 (5x5 32->8, stats) -> g3 (5x5 8->8 +bias)
    MCONV(32,32,32,2,5,false,true ,0)(feat, nullptr, nullptr, nullptr, nullptr,
        w_g1, nullptr, A1, sum+1*64, sq+1*64, nullptr, nullptr, nullptr);
    MCONV(32,32, 8,1,5,true ,true ,0)(A1, sum+1*64, sq+1*64, g1_g, g1_b,
        w_g2, nullptr, A2, sum+2*64, sq+2*64, nullptr, nullptr, nullptr);
    MCONV( 8, 8, 8,1,5,true ,false,1)(A2, sum+2*64, sq+2*64, g2_g, g2_b,
        w_g3, g3_bias, GUID, nullptr, nullptr, nullptr, nullptr, nullptr);

    // off_aff branch: oa1 (5x5 8->8, stats) -> oa2 (5x5 8->24, stats)
    //                 -> oa3 (5x5 24->24 +bias) fused with deform -> out
    MCONV( 8, 8, 8,1,5,false,true ,0)(GUID, nullptr, nullptr, nullptr, nullptr,
        w_o1, nullptr, A2, sum+3*64, sq+3*64, nullptr, nullptr, nullptr);
    MCONV( 8, 8,24,2,5,true ,true ,0)(A2, sum+3*64, sq+3*64, oa1_g, oa1_b,
        w_o2, nullptr, OA2, sum+4*64, sq+4*64, nullptr, nullptr, nullptr);
    MCONV(24,32,24,2,5,true ,false,3)(OA2, sum+4*64, sq+4*64, oa2_g, oa2_b,
        w_o3, oa3_bias, out, nullptr, nullptr, FUS, gk, aff_scale);
    #undef MCONV
}

// Round 10
// 1123.392 us; speedup vs baseline: 1.9796x; 1.2375x over previous
//
#include <hip/hip_runtime.h>
#include <hip/hip_bf16.h>
#include <math.h>

#define B_   8
#define H_   320
#define W_   320
#define HW_  (320*320)

typedef __attribute__((ext_vector_type(8))) short bf16x8;
typedef __attribute__((ext_vector_type(4))) short bf16x4s;
typedef __attribute__((ext_vector_type(4))) float f32x4;

__device__ __forceinline__ short f2b(float v){
    __hip_bfloat16 h = __float2bfloat16(v);
    return *(short*)&h;
}
__device__ __forceinline__ float bf2f(short v){
    unsigned u = ((unsigned)(unsigned short)v) << 16;
    return __uint_as_float(u);
}

// ---------------------------------------------------------------------------
// Repack ALL conv weights into MFMA A-fragment layout (bf16)  (r6-verified):
//   wr[((chunk*MT + mt)*16 + co_l)*32 + kl]  = W[co = mt*16+co_l][k = chunk*32+kl]
// K-order: k = tap*CIp + ci  (ci fastest). CIp=32: chunk=1 tap; CIp=8: 4 taps.
// Zero-padded for co>=COUT, ci>=CIN, tap>=K*K (so NHWC pad channels are 0).
// ---------------------------------------------------------------------------
__global__ void repack_k(const float* __restrict__ sf1, const float* __restrict__ sf2,
                         const float* __restrict__ sg1, const float* __restrict__ sg2,
                         const float* __restrict__ sg3, const float* __restrict__ so1,
                         const float* __restrict__ so2, const float* __restrict__ so3,
                         short* __restrict__ dst){
    const int cum[8]  = {9216,13824,39424,52224,55808,59392,66560,92160};
    const int CINs[8] = {32,32,32,32, 8, 8, 8,24};
    const int CIps[8] = {32,32,32,32, 8, 8, 8,32};
    const int COUTs[8]= {32, 1,32, 8, 8, 8,24,24};
    const int MTs[8]  = { 2, 1, 2, 1, 1, 1, 2, 2};
    const int Ks[8]   = { 3, 3, 5, 5, 5, 5, 5, 5};
    int i = blockIdx.x*256 + threadIdx.x;
    if (i >= 92160) return;
    int s = 0;
    while (i >= cum[s]) ++s;
    const int base = s ? cum[s-1] : 0;
    const int il = i - base;
    const float* src = (s==0)?sf1:(s==1)?sf2:(s==2)?sg1:(s==3)?sg2:(s==4)?sg3:(s==5)?so1:(s==6)?so2:so3;
    const int kl   = il & 31;
    const int co_l = (il >> 5) & 15;
    const int rem  = il >> 9;
    const int MT = MTs[s];
    const int mt = rem % MT;
    const int c  = rem / MT;
    int tap, ci;
    if (CIps[s] == 32){ tap = c; ci = kl; }
    else              { tap = c*4 + (kl>>3); ci = kl & 7; }
    const int K = Ks[s];
    const int co = mt*16 + co_l;
    float v = 0.f;
    if (co < COUTs[s] && ci < CINs[s] && tap < K*K){
        const int ky = tap / K, kx = tap - ky*K;
        v = src[((co*CINs[s] + ci)*K + ky)*K + kx];
    }
    dst[i] = f2b(v);
}

// ---------------------------------------------------------------------------
// Deform epilogue (verified r2-r7)
// ---------------------------------------------------------------------------
__device__ __forceinline__
float deform_px(const float* val, const float* __restrict__ fus_b,
                const float* __restrict__ gk_b, float inv_s, int y, int x){
    float aff[8]; float sa = 0.f;
    #pragma unroll
    for (int n=0;n<8;++n){
        float a = tanhf(val[16+n]) * inv_s + gk_b[n];
        aff[n] = a; sa += fabsf(a);
    }
    sa += 1e-5f;
    sa = fmaxf(sa, 1.f);
    const float isa = 1.f/sa;
    float ssum = 0.f;
    #pragma unroll
    for (int n=0;n<8;++n){ aff[n] *= isa; ssum += aff[n]; }
    const float aff_ref = 1.f - ssum;

    float o = 0.f;
    #pragma unroll
    for (int k=0;k<9;++k){
        float dy, dx, m;
        if (k == 4){ dy = 0.f; dx = 0.f; m = aff_ref; }
        else {
            const int n = (k < 4) ? k : k-1;
            dy = val[2*n];
            dx = val[2*n+1];
            m  = aff[n];
        }
        float yy = (float)(y + k/3 - 1) + dy;
        float xx = (float)(x + k%3 - 1) + dx;
        float y0f = floorf(yy), x0f = floorf(xx);
        int   y0 = (int)y0f,    x0i = (int)x0f;
        float wy1 = yy - y0f, wy0 = 1.f - wy1;
        float wx1 = xx - x0f, wx0 = 1.f - wx1;
        float v00 = (y0  >=0 && y0  <H_ && x0i  >=0 && x0i  <W_) ? fus_b[ y0   *W_ + x0i  ] : 0.f;
        float v01 = (y0  >=0 && y0  <H_ && x0i+1>=0 && x0i+1<W_) ? fus_b[ y0   *W_ + x0i+1] : 0.f;
        float v10 = (y0+1>=0 && y0+1<H_ && x0i  >=0 && x0i  <W_) ? fus_b[(y0+1)*W_ + x0i  ] : 0.f;
        float v11 = (y0+1>=0 && y0+1<H_ && x0i+1>=0 && x0i+1<W_) ? fus_b[(y0+1)*W_ + x0i+1] : 0.f;
        o += m * (wy0*(wx0*v00 + wx1*v01) + wy1*(wx0*v10 + wx1*v11));
    }
    return fabsf(o);
}

// ---------------------------------------------------------------------------
// MFMA implicit-GEMM conv.  D[co][px] = sum_k W[co][k] * im2col[k][px]
// Block: 256 thr = 4 waves; tile 32(x) x 4(y); wave w owns row y0+w, 2 N-tiles.
// IN_FMT: 0 = fp32 NCHW (external feat), 1 = bf16 NHWC (intermediates, CIp pad)
// OUT_MODE: 0 raw->NHWC bf16 (OCP pad), 1 +bias->NHWC bf16,
//           2 tanh(+bias)->fp32 HW plane (COUT=1), 3 deform epilogue -> fp32.
// LDS lds_in[y][x][STR]: STR=40 for CIp=32 (80B = 20 banks -> 2-way, free).
// *** r8/r9 BUG (fixed): BN must be applied INSIDE the bounds guard — the
// reference zero-pads AFTER bn+relu, so halo must be exactly 0, not relu(shift).
// ---------------------------------------------------------------------------
template<int CIN, int CIp, int COUT, int MT, int K, int IN_FMT,
         bool IN_BN, bool OUT_STATS, int OUT_MODE, int OCP>
__global__ __launch_bounds__(256, 4)
void mconv_k(const void* __restrict__ inv,
             const float* __restrict__ bn_sum, const float* __restrict__ bn_sq,
             const float* __restrict__ gamma, const float* __restrict__ beta,
             const short* __restrict__ wr, const float* __restrict__ bias,
             void* __restrict__ outv,
             float* __restrict__ osum, float* __restrict__ osq,
             const float* __restrict__ fus, const float* __restrict__ gk,
             const float* __restrict__ aff_scale){
    constexpr int PAD = K/2;
    constexpr int LW  = 32 + K - 1;
    constexpr int LH  = 4 + K - 1;
    constexpr int STR = (CIp==32) ? 40 : 8;     // bank-conflict pad
    constexpr int NTAPS  = K*K;
    constexpr int NCHUNK = (CIp==32) ? NTAPS : (NTAPS*CIp + 31)/32;
    constexpr int INB  = LH*LW*STR*2;
    constexpr int DUMPB = 128*33*4;             // deform dump, stride 33
    constexpr int LDSB = (OUT_MODE==3 && INB < DUMPB) ? DUMPB : INB;

    __shared__ __align__(16) char ldsraw[LDSB];
    short* lds_in = (short*)ldsraw;
    __shared__ float sc_sh[2][32];
    __shared__ float red[2][4][32];

    const int tid = threadIdx.x;
    const int b   = blockIdx.z;
    const int x0  = blockIdx.x*32, y0 = blockIdx.y*4;

    if (IN_BN){
        if (tid < 32){
            float s = 1.f, sh2 = 0.f;
            if (tid < CIN){
                const float invN = 1.f/(float)(B_*HW_);
                float mu  = bn_sum[tid]*invN;
                float var = bn_sq[tid]*invN - mu*mu;
                s   = gamma[tid] * rsqrtf(var + 1e-5f);
                sh2 = beta[tid] - mu*s;
            }
            sc_sh[0][tid] = s;
            sc_sh[1][tid] = sh2;
        }
        __syncthreads();
    }

    // ---- stage whole CIN depth as bf16 into lds_in[y][x][STR] ----
    if (IN_FMT == 0){
        // fp32 NCHW source (feat): pair-packed ds_write_b32 (r5/r7-proven)
        const float* in = (const float*)inv;
        const int sx = tid & 31;
        const int ss = tid >> 5;
        constexpr int NPAIR = CIp/2;
        for (int r = 0; r < LH; ++r){
            const int gy = y0 + r - PAD;
            const bool rok = (gy>=0) & (gy<H_);
            for (int pp = ss; pp < NPAIR; pp += 8){
                const int c0i = 2*pp, c1i = 2*pp+1;
                float sc0=1.f, sh0=0.f, sc1=1.f, sh1=0.f;
                if (IN_BN){
                    sc0 = sc_sh[0][c0i]; sh0 = sc_sh[1][c0i];
                    sc1 = sc_sh[0][c1i]; sh1 = sc_sh[1][c1i];
                }
                const float* s0 = in + ((long)b*CIN + c0i)*HW_ + gy*W_;
                const float* s1 = in + ((long)b*CIN + c1i)*HW_ + gy*W_;
                #pragma unroll
                for (int h=0; h<2; ++h){
                    const int xl = sx + h*32;
                    if (xl < LW){
                        const int gx = x0 + xl - PAD;
                        float v0 = 0.f, v1 = 0.f;
                        if (rok && gx>=0 && gx<W_){
                            if (c0i < CIN){
                                v0 = s0[gx];
                                if (IN_BN) v0 = fmaxf(fmaf(v0, sc0, sh0), 0.f);
                            }
                            if (c1i < CIN){
                                v1 = s1[gx];
                                if (IN_BN) v1 = fmaxf(fmaf(v1, sc1, sh1), 0.f);
                            }
                        }
                        unsigned u = (unsigned)(unsigned short)f2b(v0)
                                   | ((unsigned)(unsigned short)f2b(v1) << 16);
                        *(unsigned*)&lds_in[(r*LW + xl)*STR + c0i] = u;
                    }
                }
            }
        }
    } else {
        // bf16 NHWC source: coalesced 16B loads; BN **inside bounds guard**
        const short* src = (const short*)inv + (long)b*HW_*CIp;
        constexpr int SEGS = CIp/8;
        constexpr int NU = LH*LW*SEGS;
        for (int u = tid; u < NU; u += 256){
            const int r   = u / (LW*SEGS);
            const int rem = u - r*(LW*SEGS);
            const int xl  = rem / SEGS;
            const int seg = rem - xl*SEGS;
            const int gy = y0 + r - PAD, gx = x0 + xl - PAD;
            bf16x8 v = {0,0,0,0,0,0,0,0};
            if (gy>=0 && gy<H_ && gx>=0 && gx<W_){
                v = *(const bf16x8*)(src + ((long)gy*W_ + gx)*CIp + seg*8);
                if (IN_BN){
                    #pragma unroll
                    for (int j=0;j<8;++j){
                        float f = bf2f(v[j]);
                        f = fmaxf(fmaf(f, sc_sh[0][seg*8+j], sc_sh[1][seg*8+j]), 0.f);
                        v[j] = f2b(f);
                    }
                }
            }
            *(bf16x8*)&lds_in[(r*LW + xl)*STR + seg*8] = v;
        }
    }
    __syncthreads();

    const int lane = tid & 63;
    const int wv   = tid >> 6;                    // wave = y-row
    const int pxn  = lane & 15;
    const int quad = lane >> 4;

    const f32x4 zero = {0.f, 0.f, 0.f, 0.f};
    f32x4 acc[MT][2];
    #pragma unroll
    for (int m=0;m<MT;++m){ acc[m][0] = zero; acc[m][1] = zero; }

    auto bptr = [&](int c)->const short*{
        if (CIp == 32){
            const int ky = c / K, kx = c - ky*K;
            return lds_in + ((wv+ky)*LW + kx + pxn)*STR + quad*8;
        } else {
            int t = c*4 + quad;
            if (t >= NTAPS) t = 0;                // fake tap (zero weights)
            const int ky = t / K, kx = t - ky*K;
            return lds_in + ((wv+ky)*LW + kx + pxn)*STR;
        }
    };

    bf16x8 acur[MT], anxt[MT];
    #pragma unroll
    for (int m=0;m<MT;++m)
        acur[m] = *(const bf16x8*)(wr + ((m*16 + pxn)*32 + quad*8));
    const short* bp0 = bptr(0);
    bf16x8 b0c = *(const bf16x8*)bp0;
    bf16x8 b1c = *(const bf16x8*)(bp0 + 16*STR);

    for (int c=0; c<NCHUNK; ++c){
        bf16x8 b0n = b0c, b1n = b1c;
        if (c+1 < NCHUNK){
            #pragma unroll
            for (int m=0;m<MT;++m)
                anxt[m] = *(const bf16x8*)(wr + ((((c+1)*MT + m)*16 + pxn)*32 + quad*8));
            const short* bpn = bptr(c+1);
            b0n = *(const bf16x8*)bpn;
            b1n = *(const bf16x8*)(bpn + 16*STR);
        }
        #pragma unroll
        for (int m=0;m<MT;++m){
            acc[m][0] = __builtin_amdgcn_mfma_f32_16x16x32_bf16(acur[m], b0c, acc[m][0], 0,0,0);
            acc[m][1] = __builtin_amdgcn_mfma_f32_16x16x32_bf16(acur[m], b1c, acc[m][1], 0,0,0);
        }
        #pragma unroll
        for (int m=0;m<MT;++m) acur[m] = anxt[m];
        b0c = b0n; b1c = b1n;
    }

    // ---- fused BN-stats epilogue (raw pre-bias acc) ----
    if (OUT_STATS){
        #pragma unroll
        for (int m=0;m<MT;++m){
            #pragma unroll
            for (int r=0;r<4;++r){
                float v  = acc[m][0][r] + acc[m][1][r];
                float v2 = acc[m][0][r]*acc[m][0][r] + acc[m][1][r]*acc[m][1][r];
                #pragma unroll
                for (int o=1;o<16;o<<=1){
                    v  += __shfl_xor(v,  o, 64);
                    v2 += __shfl_xor(v2, o, 64);
                }
                if (pxn == 0){
                    red[0][wv][m*16 + quad*4 + r] = v;
                    red[1][wv][m*16 + quad*4 + r] = v2;
                }
            }
        }
        __syncthreads();
        if (tid < MT*16 && tid < COUT){
            atomicAdd(&osum[tid], red[0][0][tid]+red[0][1][tid]+red[0][2][tid]+red[0][3][tid]);
            atomicAdd(&osq[tid],  red[1][0][tid]+red[1][1][tid]+red[1][2][tid]+red[1][3][tid]);
        }
    }

    const int y = y0 + wv;
    if (OUT_MODE == 3){
        // gather per-pixel co-vector via LDS (stride 33), deform, write fp32
        float* out = (float*)outv;
        __syncthreads();                          // done reading lds_in
        float* dumpf = (float*)ldsraw;
        #pragma unroll
        for (int m=0;m<MT;++m)
            #pragma unroll
            for (int n=0;n<2;++n)
                #pragma unroll
                for (int r=0;r<4;++r)
                    dumpf[(wv*32 + n*16 + pxn)*33 + (m*16 + quad*4 + r)] = acc[m][n][r];
        __syncthreads();
        if (tid < 128){
            float val[24];
            #pragma unroll
            for (int c2=0;c2<24;++c2) val[c2] = dumpf[tid*33 + c2] + bias[c2];
            const int yy = y0 + (tid>>5), xx = x0 + (tid&31);
            const float inv_s = 1.f/(aff_scale[0] + 1e-5f);
            out[(long)b*HW_ + yy*W_ + xx] =
                deform_px(val, fus + (long)b*HW_, gk + b*8, inv_s, yy, xx);
        }
    } else if (OUT_MODE == 2){
        // fp32 plane output (COUT=1): tanh(acc+bias)
        float* out = (float*)outv;
        #pragma unroll
        for (int m=0;m<MT;++m){
            #pragma unroll
            for (int r=0;r<4;++r){
                const int co = m*16 + quad*4 + r;
                if (co < COUT){
                    float* op = out + (((long)b*COUT + co)*H_ + y)*W_ + x0;
                    #pragma unroll
                    for (int n=0;n<2;++n)
                        op[n*16 + pxn] = tanhf(acc[m][n][r] + bias[co]);
                }
            }
        }
    } else {
        // NHWC bf16 output, OCP channel pad; 8B bf16x4 stores, coalesced
        short* o = (short*)outv;
        #pragma unroll
        for (int m=0;m<MT;++m){
            const int co0 = m*16 + quad*4;
            if (co0 < OCP){
                #pragma unroll
                for (int n=0;n<2;++n){
                    bf16x4s pk;
                    #pragma unroll
                    for (int r=0;r<4;++r){
                        float f = acc[m][n][r];
                        if (OUT_MODE == 1) f += bias[co0+r];
                        pk[r] = f2b(f);
                    }
                    const long px = ((long)b*H_ + y)*W_ + x0 + n*16 + pxn;
                    *(bf16x4s*)(o + px*OCP + co0) = pk;
                }
            }
        }
    }
}

// ---------------------------------------------------------------------------
// Global average pool of feat -> p (B,32). One block per (b,c).
// ---------------------------------------------------------------------------
__global__ void pool_k(const float* __restrict__ feat, float* __restrict__ p){
    const int bc = blockIdx.x;
    const float* src = feat + (long)bc*HW_;
    float s = 0.f;
    for (int i=threadIdx.x; i<HW_; i+=256) s += src[i];
    #pragma unroll
    for (int off=32; off; off>>=1) s += __shfl_down(s, off, 64);
    __shared__ float red[4];
    const int lane = threadIdx.x & 63, wid = threadIdx.x >> 6;
    if (lane == 0) red[wid] = s;
    __syncthreads();
    if (threadIdx.x == 0)
        p[bc] = (red[0]+red[1]+red[2]+red[3]) * (1.f/(float)HW_);
}

// ---------------------------------------------------------------------------
// CAM MLP (32->16 celu ->16 celu ->1 relu +0.001) then gauss_win -> gk (B,8)
// ---------------------------------------------------------------------------
__global__ void sigma_k(const float* __restrict__ p,
                        const float* s1w, const float* s1b,
                        const float* s2w, const float* s2b,
                        const float* s3w, const float* s3b,
                        float* __restrict__ gk){
    const int b = threadIdx.x;
    if (b >= B_) return;
    float h1[16], h2[16];
    for (int i=0;i<16;++i){
        float t = s1b[i];
        for (int j=0;j<32;++j) t = fmaf(p[b*32+j], s1w[i*32+j], t);
        h1[i] = t > 0.f ? t : expm1f(t);          // celu(alpha=1)
    }
    for (int i=0;i<16;++i){
        float t = s2b[i];
        for (int j=0;j<16;++j) t = fmaf(h1[j], s2w[i*16+j], t);
        h2[i] = t > 0.f ? t : expm1f(t);
    }
    float t = s3b[0];
    for (int j=0;j<16;++j) t = fmaf(h2[j], s3w[j], t);
    float sigma = fmaxf(t, 0.f) + 0.001f;
    float sg = sigma + 0.2f;                      // sigma_gamma = 0.2
    float e = expf(-1.f/(2.f*sg*sg));
    float inv = 1.f/(2.f*e + 1.f);
    float a = e*inv, c = inv;                     // w1 = [a, c, a]
    float* g = gk + b*8;                          // outer(w1,w1) flat minus center
    g[0]=a*a; g[1]=a*c; g[2]=a*a; g[3]=c*a; g[4]=c*a; g[5]=a*a; g[6]=a*c; g[7]=a*a;
}

// ---------------------------------------------------------------------------
extern "C" void kernel_launch(void* const* d_in, const int* in_sizes, int n_in,
                              void* d_out, int out_size, void* d_ws, size_t ws_size,
                              hipStream_t stream){
    const float* feat    = (const float*)d_in[0];
    const float* g1_w    = (const float*)d_in[1];
    const float* g1_g    = (const float*)d_in[2];
    const float* g1_b    = (const float*)d_in[3];
    const float* g2_w    = (const float*)d_in[4];
    const float* g2_g    = (const float*)d_in[5];
    const float* g2_b    = (const float*)d_in[6];
    const float* g3_w    = (const float*)d_in[7];
    const float* g3_bias = (const float*)d_in[8];
    const float* f1_w    = (const float*)d_in[9];
    const float* f1_g    = (const float*)d_in[10];
    const float* f1_b    = (const float*)d_in[11];
    const float* f2_w    = (const float*)d_in[12];
    const float* f2_bias = (const float*)d_in[13];
    const float* s1w     = (const float*)d_in[14];
    const float* s1b     = (const float*)d_in[15];
    const float* s2w     = (const float*)d_in[16];
    const float* s2b     = (const float*)d_in[17];
    const float* s3w     = (const float*)d_in[18];
    const float* s3b     = (const float*)d_in[19];
    const float* oa1_w   = (const float*)d_in[20];
    const float* oa1_g   = (const float*)d_in[21];
    const float* oa1_b   = (const float*)d_in[22];
    const float* oa2_w   = (const float*)d_in[23];
    const float* oa2_g   = (const float*)d_in[24];
    const float* oa2_b   = (const float*)d_in[25];
    const float* oa3_w   = (const float*)d_in[26];
    const float* oa3_bias= (const float*)d_in[27];
    const float* aff_scale=(const float*)d_in[28];
    float* out = (float*)d_out;

    // workspace: bf16 NHWC intermediates
    //   A1  (32ch NHWC bf16)  52,428,800 B    (f1 out / g1 out; OA2 alias)
    //   A2  ( 8ch NHWC bf16)  13,107,200 B    (g2 out, oa1 out)
    //   GUID( 8ch NHWC bf16)  13,107,200 B
    //   FUS (fp32 HW plane)    3,276,800 B
    //   SM  (stats + p + gk + bf16 weights)    ~188 KB
    char* ws = (char*)d_ws;
    short* A1   = (short*)(ws + 0L);
    short* A2   = (short*)(ws + 52428800L);
    short* GUID = (short*)(ws + 65536000L);
    float* FUS  = (float*)(ws + 78643200L);
    float* SM   = (float*)(ws + 81920000L);
    short* OA2  = A1;   // alias: A1 dead before oa2 writes

    float* sum = SM;             // 5 slots x 64
    float* sq  = SM + 320;
    float* p   = SM + 640;       // 256
    float* gk  = SM + 896;       // 64
    short* WBs = (short*)(SM + 960);   // bf16 MFMA weights, 92160 shorts
    short* w_f1 = WBs + 0;
    short* w_f2 = WBs + 9216;
    short* w_g1 = WBs + 13824;
    short* w_g2 = WBs + 39424;
    short* w_g3 = WBs + 52224;
    short* w_o1 = WBs + 55808;
    short* w_o2 = WBs + 59392;
    short* w_o3 = WBs + 66560;

    hipMemsetAsync(sum, 0, 640*sizeof(float), stream);   // zero sum+sumsq

    repack_k<<<dim3(360), dim3(256), 0, stream>>>(
        f1_w, f2_w, g1_w, g2_w, g3_w, oa1_w, oa2_w, oa3_w, WBs);

    // sigma branch (independent)
    pool_k<<<dim3(256), dim3(256), 0, stream>>>(feat, p);
    sigma_k<<<dim3(1), dim3(64), 0, stream>>>(p, s1w, s1b, s2w, s2b, s3w, s3b, gk);

    const dim3 cgrid(10, 80, 8), cblk(256);
    #define MCONV(CIN,CIp,COUT,MT,K,IFMT,IBN,OST,OM,OCP) \
        mconv_k<CIN,CIp,COUT,MT,K,IFMT,IBN,OST,OM,OCP><<<cgrid,cblk,0,stream>>>

    // fuse branch: f1 (3x3 32->32, stats) -> f2 (bn in, 3x3 32->1, tanh)
    MCONV(32,32,32,2,3,0,false,true ,0,32)(feat, nullptr, nullptr, nullptr, nullptr,
        w_f1, nullptr, A1, sum+0*64, sq+0*64, nullptr, nullptr, nullptr);
    MCONV(32,32, 1,1,3,1,true ,false,2, 0)(A1, sum+0*64, sq+0*64, f1_g, f1_b,
        w_f2, f2_bias, FUS, nullptr, nullptr, nullptr, nullptr, nullptr);

    // guid branch: g1 (5x5 32->32, stats) -> g2 (5x5 32->8, stats) -> g3 (5x5 8->8 +bias)
    MCONV(32,32,32,2,5,0,false,true ,0,32)(feat, nullptr, nullptr, nullptr, nullptr,
        w_g1, nullptr, A1, sum+1*64, sq+1*64, nullptr, nullptr, nullptr);
    MCONV(32,32, 8,1,5,1,true ,true ,0, 8)(A1, sum+1*64, sq+1*64, g1_g, g1_b,
        w_g2, nullptr, A2, sum+2*64, sq+2*64, nullptr, nullptr, nullptr);
    MCONV( 8, 8, 8,1,5,1,true ,false,1, 8)(A2, sum+2*64, sq+2*64, g2_g, g2_b,
        w_g3, g3_bias, GUID, nullptr, nullptr, nullptr, nullptr, nullptr);

    // off_aff branch: oa1 (5x5 8->8, stats) -> oa2 (5x5 8->24, stats)
    //                 -> oa3 (5x5 24->24 +bias) fused with deform -> out
    MCONV( 8, 8, 8,1,5,1,false,true ,0, 8)(GUID, nullptr, nullptr, nullptr, nullptr,
        w_o1, nullptr, A2, sum+3*64, sq+3*64, nullptr, nullptr, nullptr);
    MCONV( 8, 8,24,2,5,1,true ,true ,0,32)(A2, sum+3*64, sq+3*64, oa1_g, oa1_b,
        w_o2, nullptr, OA2, sum+4*64, sq+4*64, nullptr, nullptr, nullptr);
    MCONV(24,32,24,2,5,1,true ,false,3, 0)(OA2, sum+4*64, sq+4*64, oa2_g, oa2_b,
        w_o3, oa3_bias, out, nullptr, nullptr, FUS, gk, aff_scale);
    #undef MCONV
}

// Round 11
// 1009.895 us; speedup vs baseline: 2.2021x; 1.1124x over previous
//
#include <hip/hip_runtime.h>
#include <hip/hip_bf16.h>
#include <math.h>

#define B_   8
#define H_   320
#define W_   320
#define HW_  (320*320)

typedef __attribute__((ext_vector_type(8))) short bf16x8;
typedef __attribute__((ext_vector_type(4))) short bf16x4s;
typedef __attribute__((ext_vector_type(4))) float f32x4;

__device__ __forceinline__ short f2b(float v){
    __hip_bfloat16 h = __float2bfloat16(v);
    return *(short*)&h;
}
__device__ __forceinline__ float bf2f(short v){
    unsigned u = ((unsigned)(unsigned short)v) << 16;
    return __uint_as_float(u);
}

// ---------------------------------------------------------------------------
// feat fp32 NCHW -> bf16 NHWC32 (one-time pre-pass; coalesced per-channel reads)
// ---------------------------------------------------------------------------
__global__ void convert_k(const float* __restrict__ in, short* __restrict__ out){
    const int b  = blockIdx.y;
    const int px = blockIdx.x*256 + threadIdx.x;
    const float* src = in + (long)b*32*HW_ + px;
    short* dst = out + ((long)b*HW_ + px)*32;
    short v[32];
    #pragma unroll
    for (int c=0;c<32;++c) v[c] = f2b(src[(long)c*HW_]);
    #pragma unroll
    for (int s=0;s<4;++s)
        *(bf16x8*)(dst + s*8) = *(bf16x8*)(v + s*8);
}

// ---------------------------------------------------------------------------
// Repack ALL conv weights into MFMA A-fragment layout (bf16)  (r6-verified):
//   wr[((chunk*MT + mt)*16 + co_l)*32 + kl]  = W[co = mt*16+co_l][k = chunk*32+kl]
// K-order: k = tap*CIp + ci  (ci fastest). CIp=32: chunk=1 tap; CIp=8: 4 taps.
// Zero-padded for co>=COUT, ci>=CIN, tap>=K*K (so NHWC pad channels are 0).
// ---------------------------------------------------------------------------
__global__ void repack_k(const float* __restrict__ sf1, const float* __restrict__ sf2,
                         const float* __restrict__ sg1, const float* __restrict__ sg2,
                         const float* __restrict__ sg3, const float* __restrict__ so1,
                         const float* __restrict__ so2, const float* __restrict__ so3,
                         short* __restrict__ dst){
    const int cum[8]  = {9216,13824,39424,52224,55808,59392,66560,92160};
    const int CINs[8] = {32,32,32,32, 8, 8, 8,24};
    const int CIps[8] = {32,32,32,32, 8, 8, 8,32};
    const int COUTs[8]= {32, 1,32, 8, 8, 8,24,24};
    const int MTs[8]  = { 2, 1, 2, 1, 1, 1, 2, 2};
    const int Ks[8]   = { 3, 3, 5, 5, 5, 5, 5, 5};
    int i = blockIdx.x*256 + threadIdx.x;
    if (i >= 92160) return;
    int s = 0;
    while (i >= cum[s]) ++s;
    const int base = s ? cum[s-1] : 0;
    const int il = i - base;
    const float* src = (s==0)?sf1:(s==1)?sf2:(s==2)?sg1:(s==3)?sg2:(s==4)?sg3:(s==5)?so1:(s==6)?so2:so3;
    const int kl   = il & 31;
    const int co_l = (il >> 5) & 15;
    const int rem  = il >> 9;
    const int MT = MTs[s];
    const int mt = rem % MT;
    const int c  = rem / MT;
    int tap, ci;
    if (CIps[s] == 32){ tap = c; ci = kl; }
    else              { tap = c*4 + (kl>>3); ci = kl & 7; }
    const int K = Ks[s];
    const int co = mt*16 + co_l;
    float v = 0.f;
    if (co < COUTs[s] && ci < CINs[s] && tap < K*K){
        const int ky = tap / K, kx = tap - ky*K;
        v = src[((co*CINs[s] + ci)*K + ky)*K + kx];
    }
    dst[i] = f2b(v);
}

// ---------------------------------------------------------------------------
// Deform epilogue (verified r2-r10)
// ---------------------------------------------------------------------------
__device__ __forceinline__
float deform_px(const float* val, const float* __restrict__ fus_b,
                const float* __restrict__ gk_b, float inv_s, int y, int x){
    float aff[8]; float sa = 0.f;
    #pragma unroll
    for (int n=0;n<8;++n){
        float a = tanhf(val[16+n]) * inv_s + gk_b[n];
        aff[n] = a; sa += fabsf(a);
    }
    sa += 1e-5f;
    sa = fmaxf(sa, 1.f);
    const float isa = 1.f/sa;
    float ssum = 0.f;
    #pragma unroll
    for (int n=0;n<8;++n){ aff[n] *= isa; ssum += aff[n]; }
    const float aff_ref = 1.f - ssum;

    float o = 0.f;
    #pragma unroll
    for (int k=0;k<9;++k){
        float dy, dx, m;
        if (k == 4){ dy = 0.f; dx = 0.f; m = aff_ref; }
        else {
            const int n = (k < 4) ? k : k-1;
            dy = val[2*n];
            dx = val[2*n+1];
            m  = aff[n];
        }
        float yy = (float)(y + k/3 - 1) + dy;
        float xx = (float)(x + k%3 - 1) + dx;
        float y0f = floorf(yy), x0f = floorf(xx);
        int   y0 = (int)y0f,    x0i = (int)x0f;
        float wy1 = yy - y0f, wy0 = 1.f - wy1;
        float wx1 = xx - x0f, wx0 = 1.f - wx1;
        float v00 = (y0  >=0 && y0  <H_ && x0i  >=0 && x0i  <W_) ? fus_b[ y0   *W_ + x0i  ] : 0.f;
        float v01 = (y0  >=0 && y0  <H_ && x0i+1>=0 && x0i+1<W_) ? fus_b[ y0   *W_ + x0i+1] : 0.f;
        float v10 = (y0+1>=0 && y0+1<H_ && x0i  >=0 && x0i  <W_) ? fus_b[(y0+1)*W_ + x0i  ] : 0.f;
        float v11 = (y0+1>=0 && y0+1<H_ && x0i+1>=0 && x0i+1<W_) ? fus_b[(y0+1)*W_ + x0i+1] : 0.f;
        o += m * (wy0*(wx0*v00 + wx1*v01) + wy1*(wx0*v10 + wx1*v11));
    }
    return fabsf(o);
}

// ---------------------------------------------------------------------------
// MFMA implicit-GEMM conv.  D[co][px] = sum_k W[co][k] * im2col[k][px]
// Block: 256 thr = 4 waves; tile 32(x) x 4(y); wave w owns row y0+w, 2 N-tiles.
// All inputs bf16 NHWC (CIp-padded; feat via convert_k pre-pass).
// OUT_MODE: 0 raw->NHWC bf16 (OCP pad), 1 +bias->NHWC bf16,
//           2 tanh(+bias)->fp32 HW plane (COUT=1), 3 deform epilogue -> fp32.
// LDS lds_in[y][x][STR]: STR=40 for CIp=32 (80B = 20 banks -> 2-way, free).
// BN applied INSIDE bounds guard (r8/r9 bug: halo must be exactly 0).
// ---------------------------------------------------------------------------
template<int CIN, int CIp, int COUT, int MT, int K,
         bool IN_BN, bool OUT_STATS, int OUT_MODE, int OCP>
__global__ __launch_bounds__(256, 4)
void mconv_k(const void* __restrict__ inv,
             const float* __restrict__ bn_sum, const float* __restrict__ bn_sq,
             const float* __restrict__ gamma, const float* __restrict__ beta,
             const short* __restrict__ wr, const float* __restrict__ bias,
             void* __restrict__ outv,
             float* __restrict__ osum, float* __restrict__ osq,
             const float* __restrict__ fus, const float* __restrict__ gk,
             const float* __restrict__ aff_scale){
    constexpr int PAD = K/2;
    constexpr int LW  = 32 + K - 1;
    constexpr int LH  = 4 + K - 1;
    constexpr int STR = (CIp==32) ? 40 : 8;     // bank-conflict pad
    constexpr int NTAPS  = K*K;
    constexpr int NCHUNK = (CIp==32) ? NTAPS : (NTAPS*CIp + 31)/32;
    constexpr int INB  = LH*LW*STR*2;
    constexpr int DUMPB = 128*33*4;             // deform dump, stride 33
    constexpr int LDSB = (OUT_MODE==3 && INB < DUMPB) ? DUMPB : INB;

    __shared__ __align__(16) char ldsraw[LDSB];
    short* lds_in = (short*)ldsraw;
    __shared__ float sc_sh[2][32];
    __shared__ float red[2][4][32];

    const int tid = threadIdx.x;
    const int b   = blockIdx.z;
    const int x0  = blockIdx.x*32, y0 = blockIdx.y*4;

    if (IN_BN){
        if (tid < 32){
            float s = 1.f, sh2 = 0.f;
            if (tid < CIN){
                const float invN = 1.f/(float)(B_*HW_);
                float mu  = bn_sum[tid]*invN;
                float var = bn_sq[tid]*invN - mu*mu;
                s   = gamma[tid] * rsqrtf(var + 1e-5f);
                sh2 = beta[tid] - mu*s;
            }
            sc_sh[0][tid] = s;
            sc_sh[1][tid] = sh2;
        }
        __syncthreads();
    }

    // ---- stage whole CIN depth: coalesced 16B NHWC loads; BN inside guard ----
    {
        const short* src = (const short*)inv + (long)b*HW_*CIp;
        constexpr int SEGS = CIp/8;
        constexpr int NU = LH*LW*SEGS;
        for (int u = tid; u < NU; u += 256){
            const int r   = u / (LW*SEGS);
            const int rem = u - r*(LW*SEGS);
            const int xl  = rem / SEGS;
            const int seg = rem - xl*SEGS;
            const int gy = y0 + r - PAD, gx = x0 + xl - PAD;
            bf16x8 v = {0,0,0,0,0,0,0,0};
            if (gy>=0 && gy<H_ && gx>=0 && gx<W_){
                v = *(const bf16x8*)(src + ((long)gy*W_ + gx)*CIp + seg*8);
                if (IN_BN){
                    #pragma unroll
                    for (int j=0;j<8;++j){
                        float f = bf2f(v[j]);
                        f = fmaxf(fmaf(f, sc_sh[0][seg*8+j], sc_sh[1][seg*8+j]), 0.f);
                        v[j] = f2b(f);
                    }
                }
            }
            *(bf16x8*)&lds_in[(r*LW + xl)*STR + seg*8] = v;
        }
    }
    __syncthreads();

    const int lane = tid & 63;
    const int wv   = tid >> 6;                    // wave = y-row
    const int pxn  = lane & 15;
    const int quad = lane >> 4;

    const f32x4 zero = {0.f, 0.f, 0.f, 0.f};
    f32x4 acc[MT][2];
    #pragma unroll
    for (int m=0;m<MT;++m){ acc[m][0] = zero; acc[m][1] = zero; }

    auto bptr = [&](int c)->const short*{
        if (CIp == 32){
            const int ky = c / K, kx = c - ky*K;
            return lds_in + ((wv+ky)*LW + kx + pxn)*STR + quad*8;
        } else {
            int t = c*4 + quad;
            if (t >= NTAPS) t = 0;                // fake tap (zero weights)
            const int ky = t / K, kx = t - ky*K;
            return lds_in + ((wv+ky)*LW + kx + pxn)*STR;
        }
    };

    bf16x8 acur[MT], anxt[MT];
    #pragma unroll
    for (int m=0;m<MT;++m)
        acur[m] = *(const bf16x8*)(wr + ((m*16 + pxn)*32 + quad*8));
    const short* bp0 = bptr(0);
    bf16x8 b0c = *(const bf16x8*)bp0;
    bf16x8 b1c = *(const bf16x8*)(bp0 + 16*STR);

    for (int c=0; c<NCHUNK; ++c){
        bf16x8 b0n = b0c, b1n = b1c;
        if (c+1 < NCHUNK){
            #pragma unroll
            for (int m=0;m<MT;++m)
                anxt[m] = *(const bf16x8*)(wr + ((((c+1)*MT + m)*16 + pxn)*32 + quad*8));
            const short* bpn = bptr(c+1);
            b0n = *(const bf16x8*)bpn;
            b1n = *(const bf16x8*)(bpn + 16*STR);
        }
        #pragma unroll
        for (int m=0;m<MT;++m){
            acc[m][0] = __builtin_amdgcn_mfma_f32_16x16x32_bf16(acur[m], b0c, acc[m][0], 0,0,0);
            acc[m][1] = __builtin_amdgcn_mfma_f32_16x16x32_bf16(acur[m], b1c, acc[m][1], 0,0,0);
        }
        #pragma unroll
        for (int m=0;m<MT;++m) acur[m] = anxt[m];
        b0c = b0n; b1c = b1n;
    }

    // ---- fused BN-stats epilogue (raw pre-bias acc) ----
    if (OUT_STATS){
        #pragma unroll
        for (int m=0;m<MT;++m){
            #pragma unroll
            for (int r=0;r<4;++r){
                float v  = acc[m][0][r] + acc[m][1][r];
                float v2 = acc[m][0][r]*acc[m][0][r] + acc[m][1][r]*acc[m][1][r];
                #pragma unroll
                for (int o=1;o<16;o<<=1){
                    v  += __shfl_xor(v,  o, 64);
                    v2 += __shfl_xor(v2, o, 64);
                }
                if (pxn == 0){
                    red[0][wv][m*16 + quad*4 + r] = v;
                    red[1][wv][m*16 + quad*4 + r] = v2;
                }
            }
        }
        __syncthreads();
        if (tid < MT*16 && tid < COUT){
            atomicAdd(&osum[tid], red[0][0][tid]+red[0][1][tid]+red[0][2][tid]+red[0][3][tid]);
            atomicAdd(&osq[tid],  red[1][0][tid]+red[1][1][tid]+red[1][2][tid]+red[1][3][tid]);
        }
    }

    const int y = y0 + wv;
    if (OUT_MODE == 3){
        // gather per-pixel co-vector via LDS (stride 33), deform, write fp32
        float* out = (float*)outv;
        __syncthreads();                          // done reading lds_in
        float* dumpf = (float*)ldsraw;
        #pragma unroll
        for (int m=0;m<MT;++m)
            #pragma unroll
            for (int n=0;n<2;++n)
                #pragma unroll
                for (int r=0;r<4;++r)
                    dumpf[(wv*32 + n*16 + pxn)*33 + (m*16 + quad*4 + r)] = acc[m][n][r];
        __syncthreads();
        if (tid < 128){
            float val[24];
            #pragma unroll
            for (int c2=0;c2<24;++c2) val[c2] = dumpf[tid*33 + c2] + bias[c2];
            const int yy = y0 + (tid>>5), xx = x0 + (tid&31);
            const float inv_s = 1.f/(aff_scale[0] + 1e-5f);
            out[(long)b*HW_ + yy*W_ + xx] =
                deform_px(val, fus + (long)b*HW_, gk + b*8, inv_s, yy, xx);
        }
    } else if (OUT_MODE == 2){
        // fp32 plane output (COUT=1): tanh(acc+bias)
        float* out = (float*)outv;
        #pragma unroll
        for (int m=0;m<MT;++m){
            #pragma unroll
            for (int r=0;r<4;++r){
                const int co = m*16 + quad*4 + r;
                if (co < COUT){
                    float* op = out + (((long)b*COUT + co)*H_ + y)*W_ + x0;
                    #pragma unroll
                    for (int n=0;n<2;++n)
                        op[n*16 + pxn] = tanhf(acc[m][n][r] + bias[co]);
                }
            }
        }
    } else {
        // NHWC bf16 output, OCP channel pad; 8B bf16x4 stores, coalesced
        short* o = (short*)outv;
        #pragma unroll
        for (int m=0;m<MT;++m){
            const int co0 = m*16 + quad*4;
            if (co0 < OCP){
                #pragma unroll
                for (int n=0;n<2;++n){
                    bf16x4s pk;
                    #pragma unroll
                    for (int r=0;r<4;++r){
                        float f = acc[m][n][r];
                        if (OUT_MODE == 1) f += bias[co0+r];
                        pk[r] = f2b(f);
                    }
                    const long px = ((long)b*H_ + y)*W_ + x0 + n*16 + pxn;
                    *(bf16x4s*)(o + px*OCP + co0) = pk;
                }
            }
        }
    }
}

// ---------------------------------------------------------------------------
// Global average pool of feat -> p (B,32). One block per (b,c).
// ---------------------------------------------------------------------------
__global__ void pool_k(const float* __restrict__ feat, float* __restrict__ p){
    const int bc = blockIdx.x;
    const float* src = feat + (long)bc*HW_;
    float s = 0.f;
    for (int i=threadIdx.x; i<HW_; i+=256) s += src[i];
    #pragma unroll
    for (int off=32; off; off>>=1) s += __shfl_down(s, off, 64);
    __shared__ float red[4];
    const int lane = threadIdx.x & 63, wid = threadIdx.x >> 6;
    if (lane == 0) red[wid] = s;
    __syncthreads();
    if (threadIdx.x == 0)
        p[bc] = (red[0]+red[1]+red[2]+red[3]) * (1.f/(float)HW_);
}

// ---------------------------------------------------------------------------
// CAM MLP (32->16 celu ->16 celu ->1 relu +0.001) then gauss_win -> gk (B,8)
// ---------------------------------------------------------------------------
__global__ void sigma_k(const float* __restrict__ p,
                        const float* s1w, const float* s1b,
                        const float* s2w, const float* s2b,
                        const float* s3w, const float* s3b,
                        float* __restrict__ gk){
    const int b = threadIdx.x;
    if (b >= B_) return;
    float h1[16], h2[16];
    for (int i=0;i<16;++i){
        float t = s1b[i];
        for (int j=0;j<32;++j) t = fmaf(p[b*32+j], s1w[i*32+j], t);
        h1[i] = t > 0.f ? t : expm1f(t);          // celu(alpha=1)
    }
    for (int i=0;i<16;++i){
        float t = s2b[i];
        for (int j=0;j<16;++j) t = fmaf(h1[j], s2w[i*16+j], t);
        h2[i] = t > 0.f ? t : expm1f(t);
    }
    float t = s3b[0];
    for (int j=0;j<16;++j) t = fmaf(h2[j], s3w[j], t);
    float sigma = fmaxf(t, 0.f) + 0.001f;
    float sg = sigma + 0.2f;                      // sigma_gamma = 0.2
    float e = expf(-1.f/(2.f*sg*sg));
    float inv = 1.f/(2.f*e + 1.f);
    float a = e*inv, c = inv;                     // w1 = [a, c, a]
    float* g = gk + b*8;                          // outer(w1,w1) flat minus center
    g[0]=a*a; g[1]=a*c; g[2]=a*a; g[3]=c*a; g[4]=c*a; g[5]=a*a; g[6]=a*c; g[7]=a*a;
}

// ---------------------------------------------------------------------------
extern "C" void kernel_launch(void* const* d_in, const int* in_sizes, int n_in,
                              void* d_out, int out_size, void* d_ws, size_t ws_size,
                              hipStream_t stream){
    const float* feat    = (const float*)d_in[0];
    const float* g1_w    = (const float*)d_in[1];
    const float* g1_g    = (const float*)d_in[2];
    const float* g1_b    = (const float*)d_in[3];
    const float* g2_w    = (const float*)d_in[4];
    const float* g2_g    = (const float*)d_in[5];
    const float* g2_b    = (const float*)d_in[6];
    const float* g3_w    = (const float*)d_in[7];
    const float* g3_bias = (const float*)d_in[8];
    const float* f1_w    = (const float*)d_in[9];
    const float* f1_g    = (const float*)d_in[10];
    const float* f1_b    = (const float*)d_in[11];
    const float* f2_w    = (const float*)d_in[12];
    const float* f2_bias = (const float*)d_in[13];
    const float* s1w     = (const float*)d_in[14];
    const float* s1b     = (const float*)d_in[15];
    const float* s2w     = (const float*)d_in[16];
    const float* s2b     = (const float*)d_in[17];
    const float* s3w     = (const float*)d_in[18];
    const float* s3b     = (const float*)d_in[19];
    const float* oa1_w   = (const float*)d_in[20];
    const float* oa1_g   = (const float*)d_in[21];
    const float* oa1_b   = (const float*)d_in[22];
    const float* oa2_w   = (const float*)d_in[23];
    const float* oa2_g   = (const float*)d_in[24];
    const float* oa2_b   = (const float*)d_in[25];
    const float* oa3_w   = (const float*)d_in[26];
    const float* oa3_bias= (const float*)d_in[27];
    const float* aff_scale=(const float*)d_in[28];
    float* out = (float*)d_out;

    // workspace: bf16 NHWC intermediates
    //   FEAT(32ch NHWC bf16)  52,428,800 B    (convert_k pre-pass)
    //   A1  (32ch NHWC bf16)  52,428,800 B    (f1 out / g1 out; OA2 alias)
    //   A2  ( 8ch NHWC bf16)  13,107,200 B    (g2 out, oa1 out)
    //   GUID( 8ch NHWC bf16)  13,107,200 B
    //   FUS (fp32 HW plane)    3,276,800 B
    //   SM  (stats + p + gk + bf16 weights)    ~188 KB
    char* ws = (char*)d_ws;
    short* FEAT = (short*)(ws + 0L);
    short* A1   = (short*)(ws + 52428800L);
    short* A2   = (short*)(ws + 104857600L);
    short* GUID = (short*)(ws + 117964800L);
    float* FUS  = (float*)(ws + 131072000L);
    float* SM   = (float*)(ws + 134348800L);
    short* OA2  = A1;   // alias: A1 dead before oa2 writes

    float* sum = SM;             // 5 slots x 64
    float* sq  = SM + 320;
    float* p   = SM + 640;       // 256
    float* gk  = SM + 896;       // 64
    short* WBs = (short*)(SM + 960);   // bf16 MFMA weights, 92160 shorts
    short* w_f1 = WBs + 0;
    short* w_f2 = WBs + 9216;
    short* w_g1 = WBs + 13824;
    short* w_g2 = WBs + 39424;
    short* w_g3 = WBs + 52224;
    short* w_o1 = WBs + 55808;
    short* w_o2 = WBs + 59392;
    short* w_o3 = WBs + 66560;

    hipMemsetAsync(sum, 0, 640*sizeof(float), stream);   // zero sum+sumsq

    repack_k<<<dim3(360), dim3(256), 0, stream>>>(
        f1_w, f2_w, g1_w, g2_w, g3_w, oa1_w, oa2_w, oa3_w, WBs);
    convert_k<<<dim3(HW_/256, B_), dim3(256), 0, stream>>>(feat, FEAT);

    // sigma branch (independent)
    pool_k<<<dim3(256), dim3(256), 0, stream>>>(feat, p);
    sigma_k<<<dim3(1), dim3(64), 0, stream>>>(p, s1w, s1b, s2w, s2b, s3w, s3b, gk);

    const dim3 cgrid(10, 80, 8), cblk(256);
    #define MCONV(CIN,CIp,COUT,MT,K,IBN,OST,OM,OCP) \
        mconv_k<CIN,CIp,COUT,MT,K,IBN,OST,OM,OCP><<<cgrid,cblk,0,stream>>>

    // fuse branch: f1 (3x3 32->32, stats) -> f2 (bn in, 3x3 32->1, tanh)
    MCONV(32,32,32,2,3,false,true ,0,32)(FEAT, nullptr, nullptr, nullptr, nullptr,
        w_f1, nullptr, A1, sum+0*64, sq+0*64, nullptr, nullptr, nullptr);
    MCONV(32,32, 1,1,3,true ,false,2, 0)(A1, sum+0*64, sq+0*64, f1_g, f1_b,
        w_f2, f2_bias, FUS, nullptr, nullptr, nullptr, nullptr, nullptr);

    // guid branch: g1 (5x5 32->32, stats) -> g2 (5x5 32->8, stats) -> g3 (5x5 8->8 +bias)
    MCONV(32,32,32,2,5,false,true ,0,32)(FEAT, nullptr, nullptr, nullptr, nullptr,
        w_g1, nullptr, A1, sum+1*64, sq+1*64, nullptr, nullptr, nullptr);
    MCONV(32,32, 8,1,5,true ,true ,0, 8)(A1, sum+1*64, sq+1*64, g1_g, g1_b,
        w_g2, nullptr, A2, sum+2*64, sq+2*64, nullptr, nullptr, nullptr);
    MCONV( 8, 8, 8,1,5,true ,false,1, 8)(A2, sum+2*64, sq+2*64, g2_g, g2_b,
        w_g3, g3_bias, GUID, nullptr, nullptr, nullptr, nullptr, nullptr);

    // off_aff branch: oa1 (5x5 8->8, stats) -> oa2 (5x5 8->24, stats)
    //                 -> oa3 (5x5 24->24 +bias) fused with deform -> out
    MCONV( 8, 8, 8,1,5,false,true ,0, 8)(GUID, nullptr, nullptr, nullptr, nullptr,
        w_o1, nullptr, A2, sum+3*64, sq+3*64, nullptr, nullptr, nullptr);
    MCONV( 8, 8,24,2,5,true ,true ,0,32)(A2, sum+3*64, sq+3*64, oa1_g, oa1_b,
        w_o2, nullptr, OA2, sum+4*64, sq+4*64, nullptr, nullptr, nullptr);
    MCONV(24,32,24,2,5,true ,false,3, 0)(OA2, sum+4*64, sq+4*64, oa2_g, oa2_b,
        w_o3, oa3_bias, out, nullptr, nullptr, FUS, gk, aff_scale);
    #undef MCONV
}

// Round 12
// 762.729 us; speedup vs baseline: 2.9157x; 1.3241x over previous
//
#include <hip/hip_runtime.h>
#include <hip/hip_bf16.h>
#include <math.h>

#define B_   8
#define H_   320
#define W_   320
#define HW_  (320*320)

typedef __attribute__((ext_vector_type(8))) short bf16x8;
typedef __attribute__((ext_vector_type(4))) short bf16x4s;
typedef __attribute__((ext_vector_type(4))) float f32x4;

__device__ __forceinline__ short f2b(float v){
    __hip_bfloat16 h = __float2bfloat16(v);
    return *(short*)&h;
}
__device__ __forceinline__ float bf2f(short v){
    unsigned u = ((unsigned)(unsigned short)v) << 16;
    return __uint_as_float(u);
}

// ---------------------------------------------------------------------------
// feat fp32 NCHW -> bf16 NHWC32 (one-time pre-pass; coalesced per-channel reads)
// ---------------------------------------------------------------------------
__global__ void convert_k(const float* __restrict__ in, short* __restrict__ out){
    const int b  = blockIdx.y;
    const int px = blockIdx.x*256 + threadIdx.x;
    const float* src = in + (long)b*32*HW_ + px;
    short* dst = out + ((long)b*HW_ + px)*32;
    short v[32];
    #pragma unroll
    for (int c=0;c<32;++c) v[c] = f2b(src[(long)c*HW_]);
    #pragma unroll
    for (int s=0;s<4;++s)
        *(bf16x8*)(dst + s*8) = *(bf16x8*)(v + s*8);
}

// ---------------------------------------------------------------------------
// Repack ALL conv weights into MFMA A-fragment layout (bf16)  (r6-verified):
//   wr[((chunk*MT + mt)*16 + co_l)*32 + kl]  = W[co = mt*16+co_l][k = chunk*32+kl]
// K-order: k = tap*CIp + ci  (ci fastest). CIp=32: chunk=1 tap; CIp=8: 4 taps.
// Zero-padded for co>=COUT, ci>=CIN, tap>=K*K (so NHWC pad channels are 0).
// ---------------------------------------------------------------------------
__global__ void repack_k(const float* __restrict__ sf1, const float* __restrict__ sf2,
                         const float* __restrict__ sg1, const float* __restrict__ sg2,
                         const float* __restrict__ sg3, const float* __restrict__ so1,
                         const float* __restrict__ so2, const float* __restrict__ so3,
                         short* __restrict__ dst){
    const int cum[8]  = {9216,13824,39424,52224,55808,59392,66560,92160};
    const int CINs[8] = {32,32,32,32, 8, 8, 8,24};
    const int CIps[8] = {32,32,32,32, 8, 8, 8,32};
    const int COUTs[8]= {32, 1,32, 8, 8, 8,24,24};
    const int MTs[8]  = { 2, 1, 2, 1, 1, 1, 2, 2};
    const int Ks[8]   = { 3, 3, 5, 5, 5, 5, 5, 5};
    int i = blockIdx.x*256 + threadIdx.x;
    if (i >= 92160) return;
    int s = 0;
    while (i >= cum[s]) ++s;
    const int base = s ? cum[s-1] : 0;
    const int il = i - base;
    const float* src = (s==0)?sf1:(s==1)?sf2:(s==2)?sg1:(s==3)?sg2:(s==4)?sg3:(s==5)?so1:(s==6)?so2:so3;
    const int kl   = il & 31;
    const int co_l = (il >> 5) & 15;
    const int rem  = il >> 9;
    const int MT = MTs[s];
    const int mt = rem % MT;
    const int c  = rem / MT;
    int tap, ci;
    if (CIps[s] == 32){ tap = c; ci = kl; }
    else              { tap = c*4 + (kl>>3); ci = kl & 7; }
    const int K = Ks[s];
    const int co = mt*16 + co_l;
    float v = 0.f;
    if (co < COUTs[s] && ci < CINs[s] && tap < K*K){
        const int ky = tap / K, kx = tap - ky*K;
        v = src[((co*CINs[s] + ci)*K + ky)*K + kx];
    }
    dst[i] = f2b(v);
}

// ---------------------------------------------------------------------------
// Deform epilogue (verified r2-r11)
// ---------------------------------------------------------------------------
__device__ __forceinline__
float deform_px(const float* val, const float* __restrict__ fus_b,
                const float* __restrict__ gk_b, float inv_s, int y, int x){
    float aff[8]; float sa = 0.f;
    #pragma unroll
    for (int n=0;n<8;++n){
        float a = tanhf(val[16+n]) * inv_s + gk_b[n];
        aff[n] = a; sa += fabsf(a);
    }
    sa += 1e-5f;
    sa = fmaxf(sa, 1.f);
    const float isa = 1.f/sa;
    float ssum = 0.f;
    #pragma unroll
    for (int n=0;n<8;++n){ aff[n] *= isa; ssum += aff[n]; }
    const float aff_ref = 1.f - ssum;

    float o = 0.f;
    #pragma unroll
    for (int k=0;k<9;++k){
        float dy, dx, m;
        if (k == 4){ dy = 0.f; dx = 0.f; m = aff_ref; }
        else {
            const int n = (k < 4) ? k : k-1;
            dy = val[2*n];
            dx = val[2*n+1];
            m  = aff[n];
        }
        float yy = (float)(y + k/3 - 1) + dy;
        float xx = (float)(x + k%3 - 1) + dx;
        float y0f = floorf(yy), x0f = floorf(xx);
        int   y0 = (int)y0f,    x0i = (int)x0f;
        float wy1 = yy - y0f, wy0 = 1.f - wy1;
        float wx1 = xx - x0f, wx0 = 1.f - wx1;
        float v00 = (y0  >=0 && y0  <H_ && x0i  >=0 && x0i  <W_) ? fus_b[ y0   *W_ + x0i  ] : 0.f;
        float v01 = (y0  >=0 && y0  <H_ && x0i+1>=0 && x0i+1<W_) ? fus_b[ y0   *W_ + x0i+1] : 0.f;
        float v10 = (y0+1>=0 && y0+1<H_ && x0i  >=0 && x0i  <W_) ? fus_b[(y0+1)*W_ + x0i  ] : 0.f;
        float v11 = (y0+1>=0 && y0+1<H_ && x0i+1>=0 && x0i+1<W_) ? fus_b[(y0+1)*W_ + x0i+1] : 0.f;
        o += m * (wy0*(wx0*v00 + wx1*v01) + wy1*(wx0*v10 + wx1*v11));
    }
    return fabsf(o);
}

// ---------------------------------------------------------------------------
// MFMA implicit-GEMM conv.  D[co][px] = sum_k W[co][k] * im2col[k][px]
// r12: tile 32(x) x 8(y); 4 waves, wave wv owns rows {wv, wv+4}, 2 N-tiles
// each -> 4 B-reads feed 4*MT MFMAs per chunk (2x matrix density vs r11's
// 32x4; halo 2.25 -> 1.69).  All inputs bf16 NHWC (CIp-padded).
// OUT_MODE: 0 raw->NHWC bf16 (OCP pad), 1 +bias->NHWC bf16,
//           2 tanh(+bias)->fp32 HW plane (COUT=1), 3 deform epilogue -> fp32.
// LDS lds_in[y][x][STR]: STR=40 for CIp=32 (80B = 20 banks -> 2-way, free).
// BN applied INSIDE bounds guard (r8/r9 bug: halo must be exactly 0).
// ---------------------------------------------------------------------------
template<int CIN, int CIp, int COUT, int MT, int K,
         bool IN_BN, bool OUT_STATS, int OUT_MODE, int OCP>
__global__ __launch_bounds__(256, 4)
void mconv_k(const void* __restrict__ inv,
             const float* __restrict__ bn_sum, const float* __restrict__ bn_sq,
             const float* __restrict__ gamma, const float* __restrict__ beta,
             const short* __restrict__ wr, const float* __restrict__ bias,
             void* __restrict__ outv,
             float* __restrict__ osum, float* __restrict__ osq,
             const float* __restrict__ fus, const float* __restrict__ gk,
             const float* __restrict__ aff_scale){
    constexpr int PAD = K/2;
    constexpr int TH  = 8;                      // tile height
    constexpr int LW  = 32 + K - 1;
    constexpr int LH  = TH + K - 1;
    constexpr int STR = (CIp==32) ? 40 : 8;     // bank-conflict pad
    constexpr int NTAPS  = K*K;
    constexpr int NCHUNK = (CIp==32) ? NTAPS : (NTAPS*CIp + 31)/32;
    constexpr int INB  = LH*LW*STR*2;
    constexpr int DUMPB = 256*33*4;             // deform dump, stride 33
    constexpr int LDSB = (OUT_MODE==3 && INB < DUMPB) ? DUMPB : INB;

    __shared__ __align__(16) char ldsraw[LDSB];
    short* lds_in = (short*)ldsraw;
    __shared__ float sc_sh[2][32];
    __shared__ float red[2][4][32];

    const int tid = threadIdx.x;
    const int b   = blockIdx.z;
    const int x0  = blockIdx.x*32, y0 = blockIdx.y*TH;

    if (IN_BN){
        if (tid < 32){
            float s = 1.f, sh2 = 0.f;
            if (tid < CIN){
                const float invN = 1.f/(float)(B_*HW_);
                float mu  = bn_sum[tid]*invN;
                float var = bn_sq[tid]*invN - mu*mu;
                s   = gamma[tid] * rsqrtf(var + 1e-5f);
                sh2 = beta[tid] - mu*s;
            }
            sc_sh[0][tid] = s;
            sc_sh[1][tid] = sh2;
        }
        __syncthreads();
    }

    // ---- stage whole CIN depth: coalesced 16B NHWC loads; BN inside guard ----
    {
        const short* src = (const short*)inv + (long)b*HW_*CIp;
        constexpr int SEGS = CIp/8;
        constexpr int NU = LH*LW*SEGS;
        for (int u = tid; u < NU; u += 256){
            const int r   = u / (LW*SEGS);
            const int rem = u - r*(LW*SEGS);
            const int xl  = rem / SEGS;
            const int seg = rem - xl*SEGS;
            const int gy = y0 + r - PAD, gx = x0 + xl - PAD;
            bf16x8 v = {0,0,0,0,0,0,0,0};
            if (gy>=0 && gy<H_ && gx>=0 && gx<W_){
                v = *(const bf16x8*)(src + ((long)gy*W_ + gx)*CIp + seg*8);
                if (IN_BN){
                    #pragma unroll
                    for (int j=0;j<8;++j){
                        float f = bf2f(v[j]);
                        f = fmaxf(fmaf(f, sc_sh[0][seg*8+j], sc_sh[1][seg*8+j]), 0.f);
                        v[j] = f2b(f);
                    }
                }
            }
            *(bf16x8*)&lds_in[(r*LW + xl)*STR + seg*8] = v;
        }
    }
    __syncthreads();

    const int lane = tid & 63;
    const int wv   = tid >> 6;                    // wave owns rows wv, wv+4
    const int pxn  = lane & 15;
    const int quad = lane >> 4;

    const f32x4 zero = {0.f, 0.f, 0.f, 0.f};
    f32x4 acc[2][MT][2];                          // [row][mt][ntile]
    #pragma unroll
    for (int rr=0;rr<2;++rr)
        #pragma unroll
        for (int m=0;m<MT;++m){ acc[rr][m][0] = zero; acc[rr][m][1] = zero; }

    auto bptr = [&](int c, int rr)->const short*{
        const int row = wv + rr*4;
        if (CIp == 32){
            const int ky = c / K, kx = c - ky*K;
            return lds_in + ((row+ky)*LW + kx + pxn)*STR + quad*8;
        } else {
            int t = c*4 + quad;
            if (t >= NTAPS) t = 0;                // fake tap (zero weights)
            const int ky = t / K, kx = t - ky*K;
            return lds_in + ((row+ky)*LW + kx + pxn)*STR;
        }
    };

    bf16x8 acur[MT], anxt[MT];
    #pragma unroll
    for (int m=0;m<MT;++m)
        acur[m] = *(const bf16x8*)(wr + ((m*16 + pxn)*32 + quad*8));
    bf16x8 bc[2][2];
    #pragma unroll
    for (int rr=0;rr<2;++rr){
        const short* bp = bptr(0, rr);
        bc[rr][0] = *(const bf16x8*)bp;
        bc[rr][1] = *(const bf16x8*)(bp + 16*STR);
    }

    for (int c=0; c<NCHUNK; ++c){
        bf16x8 bn[2][2];
        #pragma unroll
        for (int rr=0;rr<2;++rr){ bn[rr][0] = bc[rr][0]; bn[rr][1] = bc[rr][1]; }
        if (c+1 < NCHUNK){
            #pragma unroll
            for (int m=0;m<MT;++m)
                anxt[m] = *(const bf16x8*)(wr + ((((c+1)*MT + m)*16 + pxn)*32 + quad*8));
            #pragma unroll
            for (int rr=0;rr<2;++rr){
                const short* bpn = bptr(c+1, rr);
                bn[rr][0] = *(const bf16x8*)bpn;
                bn[rr][1] = *(const bf16x8*)(bpn + 16*STR);
            }
        }
        #pragma unroll
        for (int m=0;m<MT;++m)
            #pragma unroll
            for (int rr=0;rr<2;++rr){
                acc[rr][m][0] = __builtin_amdgcn_mfma_f32_16x16x32_bf16(acur[m], bc[rr][0], acc[rr][m][0], 0,0,0);
                acc[rr][m][1] = __builtin_amdgcn_mfma_f32_16x16x32_bf16(acur[m], bc[rr][1], acc[rr][m][1], 0,0,0);
            }
        #pragma unroll
        for (int m=0;m<MT;++m) acur[m] = anxt[m];
        #pragma unroll
        for (int rr=0;rr<2;++rr){ bc[rr][0] = bn[rr][0]; bc[rr][1] = bn[rr][1]; }
    }

    // ---- fused BN-stats epilogue (raw pre-bias acc) ----
    if (OUT_STATS){
        #pragma unroll
        for (int m=0;m<MT;++m){
            #pragma unroll
            for (int r=0;r<4;++r){
                float v  = acc[0][m][0][r] + acc[0][m][1][r]
                         + acc[1][m][0][r] + acc[1][m][1][r];
                float v2 = acc[0][m][0][r]*acc[0][m][0][r] + acc[0][m][1][r]*acc[0][m][1][r]
                         + acc[1][m][0][r]*acc[1][m][0][r] + acc[1][m][1][r]*acc[1][m][1][r];
                #pragma unroll
                for (int o=1;o<16;o<<=1){
                    v  += __shfl_xor(v,  o, 64);
                    v2 += __shfl_xor(v2, o, 64);
                }
                if (pxn == 0){
                    red[0][wv][m*16 + quad*4 + r] = v;
                    red[1][wv][m*16 + quad*4 + r] = v2;
                }
            }
        }
        __syncthreads();
        if (tid < MT*16 && tid < COUT){
            atomicAdd(&osum[tid], red[0][0][tid]+red[0][1][tid]+red[0][2][tid]+red[0][3][tid]);
            atomicAdd(&osq[tid],  red[1][0][tid]+red[1][1][tid]+red[1][2][tid]+red[1][3][tid]);
        }
    }

    if (OUT_MODE == 3){
        // gather per-pixel co-vector via LDS (stride 33), deform, write fp32
        float* out = (float*)outv;
        __syncthreads();                          // done reading lds_in
        float* dumpf = (float*)ldsraw;
        #pragma unroll
        for (int rr=0;rr<2;++rr){
            const int row = wv + rr*4;
            #pragma unroll
            for (int m=0;m<MT;++m)
                #pragma unroll
                for (int n=0;n<2;++n)
                    #pragma unroll
                    for (int r=0;r<4;++r)
                        dumpf[(row*32 + n*16 + pxn)*33 + (m*16 + quad*4 + r)] = acc[rr][m][n][r];
        }
        __syncthreads();
        {
            float val[24];
            #pragma unroll
            for (int c2=0;c2<24;++c2) val[c2] = dumpf[tid*33 + c2] + bias[c2];
            const int yy = y0 + (tid>>5), xx = x0 + (tid&31);
            const float inv_s = 1.f/(aff_scale[0] + 1e-5f);
            out[(long)b*HW_ + yy*W_ + xx] =
                deform_px(val, fus + (long)b*HW_, gk + b*8, inv_s, yy, xx);
        }
    } else if (OUT_MODE == 2){
        // fp32 plane output (COUT=1): tanh(acc+bias)
        float* out = (float*)outv;
        #pragma unroll
        for (int rr=0;rr<2;++rr){
            const int y = y0 + wv + rr*4;
            #pragma unroll
            for (int m=0;m<MT;++m){
                #pragma unroll
                for (int r=0;r<4;++r){
                    const int co = m*16 + quad*4 + r;
                    if (co < COUT){
                        float* op = out + (((long)b*COUT + co)*H_ + y)*W_ + x0;
                        #pragma unroll
                        for (int n=0;n<2;++n)
                            op[n*16 + pxn] = tanhf(acc[rr][m][n][r] + bias[co]);
                    }
                }
            }
        }
    } else {
        // NHWC bf16 output, OCP channel pad; 8B bf16x4 stores, coalesced
        short* o = (short*)outv;
        #pragma unroll
        for (int rr=0;rr<2;++rr){
            const int y = y0 + wv + rr*4;
            #pragma unroll
            for (int m=0;m<MT;++m){
                const int co0 = m*16 + quad*4;
                if (co0 < OCP){
                    #pragma unroll
                    for (int n=0;n<2;++n){
                        bf16x4s pk;
                        #pragma unroll
                        for (int r=0;r<4;++r){
                            float f = acc[rr][m][n][r];
                            if (OUT_MODE == 1) f += bias[co0+r];
                            pk[r] = f2b(f);
                        }
                        const long px = ((long)b*H_ + y)*W_ + x0 + n*16 + pxn;
                        *(bf16x4s*)(o + px*OCP + co0) = pk;
                    }
                }
            }
        }
    }
}

// ---------------------------------------------------------------------------
// Global average pool of feat -> p (B,32). One block per (b,c).
// ---------------------------------------------------------------------------
__global__ void pool_k(const float* __restrict__ feat, float* __restrict__ p){
    const int bc = blockIdx.x;
    const float* src = feat + (long)bc*HW_;
    float s = 0.f;
    for (int i=threadIdx.x; i<HW_; i+=256) s += src[i];
    #pragma unroll
    for (int off=32; off; off>>=1) s += __shfl_down(s, off, 64);
    __shared__ float red[4];
    const int lane = threadIdx.x & 63, wid = threadIdx.x >> 6;
    if (lane == 0) red[wid] = s;
    __syncthreads();
    if (threadIdx.x == 0)
        p[bc] = (red[0]+red[1]+red[2]+red[3]) * (1.f/(float)HW_);
}

// ---------------------------------------------------------------------------
// CAM MLP (32->16 celu ->16 celu ->1 relu +0.001) then gauss_win -> gk (B,8)
// ---------------------------------------------------------------------------
__global__ void sigma_k(const float* __restrict__ p,
                        const float* s1w, const float* s1b,
                        const float* s2w, const float* s2b,
                        const float* s3w, const float* s3b,
                        float* __restrict__ gk){
    const int b = threadIdx.x;
    if (b >= B_) return;
    float h1[16], h2[16];
    for (int i=0;i<16;++i){
        float t = s1b[i];
        for (int j=0;j<32;++j) t = fmaf(p[b*32+j], s1w[i*32+j], t);
        h1[i] = t > 0.f ? t : expm1f(t);          // celu(alpha=1)
    }
    for (int i=0;i<16;++i){
        float t = s2b[i];
        for (int j=0;j<16;++j) t = fmaf(h1[j], s2w[i*16+j], t);
        h2[i] = t > 0.f ? t : expm1f(t);
    }
    float t = s3b[0];
    for (int j=0;j<16;++j) t = fmaf(h2[j], s3w[j], t);
    float sigma = fmaxf(t, 0.f) + 0.001f;
    float sg = sigma + 0.2f;                      // sigma_gamma = 0.2
    float e = expf(-1.f/(2.f*sg*sg));
    float inv = 1.f/(2.f*e + 1.f);
    float a = e*inv, c = inv;                     // w1 = [a, c, a]
    float* g = gk + b*8;                          // outer(w1,w1) flat minus center
    g[0]=a*a; g[1]=a*c; g[2]=a*a; g[3]=c*a; g[4]=c*a; g[5]=a*a; g[6]=a*c; g[7]=a*a;
}

// ---------------------------------------------------------------------------
extern "C" void kernel_launch(void* const* d_in, const int* in_sizes, int n_in,
                              void* d_out, int out_size, void* d_ws, size_t ws_size,
                              hipStream_t stream){
    const float* feat    = (const float*)d_in[0];
    const float* g1_w    = (const float*)d_in[1];
    const float* g1_g    = (const float*)d_in[2];
    const float* g1_b    = (const float*)d_in[3];
    const float* g2_w    = (const float*)d_in[4];
    const float* g2_g    = (const float*)d_in[5];
    const float* g2_b    = (const float*)d_in[6];
    const float* g3_w    = (const float*)d_in[7];
    const float* g3_bias = (const float*)d_in[8];
    const float* f1_w    = (const float*)d_in[9];
    const float* f1_g    = (const float*)d_in[10];
    const float* f1_b    = (const float*)d_in[11];
    const float* f2_w    = (const float*)d_in[12];
    const float* f2_bias = (const float*)d_in[13];
    const float* s1w     = (const float*)d_in[14];
    const float* s1b     = (const float*)d_in[15];
    const float* s2w     = (const float*)d_in[16];
    const float* s2b     = (const float*)d_in[17];
    const float* s3w     = (const float*)d_in[18];
    const float* s3b     = (const float*)d_in[19];
    const float* oa1_w   = (const float*)d_in[20];
    const float* oa1_g   = (const float*)d_in[21];
    const float* oa1_b   = (const float*)d_in[22];
    const float* oa2_w   = (const float*)d_in[23];
    const float* oa2_g   = (const float*)d_in[24];
    const float* oa2_b   = (const float*)d_in[25];
    const float* oa3_w   = (const float*)d_in[26];
    const float* oa3_bias= (const float*)d_in[27];
    const float* aff_scale=(const float*)d_in[28];
    float* out = (float*)d_out;

    // workspace: bf16 NHWC intermediates
    char* ws = (char*)d_ws;
    short* FEAT = (short*)(ws + 0L);
    short* A1   = (short*)(ws + 52428800L);
    short* A2   = (short*)(ws + 104857600L);
    short* GUID = (short*)(ws + 117964800L);
    float* FUS  = (float*)(ws + 131072000L);
    float* SM   = (float*)(ws + 134348800L);
    short* OA2  = A1;   // alias: A1 dead before oa2 writes

    float* sum = SM;             // 5 slots x 64
    float* sq  = SM + 320;
    float* p   = SM + 640;       // 256
    float* gk  = SM + 896;       // 64
    short* WBs = (short*)(SM + 960);   // bf16 MFMA weights, 92160 shorts
    short* w_f1 = WBs + 0;
    short* w_f2 = WBs + 9216;
    short* w_g1 = WBs + 13824;
    short* w_g2 = WBs + 39424;
    short* w_g3 = WBs + 52224;
    short* w_o1 = WBs + 55808;
    short* w_o2 = WBs + 59392;
    short* w_o3 = WBs + 66560;

    hipMemsetAsync(sum, 0, 640*sizeof(float), stream);   // zero sum+sumsq

    repack_k<<<dim3(360), dim3(256), 0, stream>>>(
        f1_w, f2_w, g1_w, g2_w, g3_w, oa1_w, oa2_w, oa3_w, WBs);
    convert_k<<<dim3(HW_/256, B_), dim3(256), 0, stream>>>(feat, FEAT);

    // sigma branch (independent)
    pool_k<<<dim3(256), dim3(256), 0, stream>>>(feat, p);
    sigma_k<<<dim3(1), dim3(64), 0, stream>>>(p, s1w, s1b, s2w, s2b, s3w, s3b, gk);

    const dim3 cgrid(10, 40, 8), cblk(256);
    #define MCONV(CIN,CIp,COUT,MT,K,IBN,OST,OM,OCP) \
        mconv_k<CIN,CIp,COUT,MT,K,IBN,OST,OM,OCP><<<cgrid,cblk,0,stream>>>

    // fuse branch: f1 (3x3 32->32, stats) -> f2 (bn in, 3x3 32->1, tanh)
    MCONV(32,32,32,2,3,false,true ,0,32)(FEAT, nullptr, nullptr, nullptr, nullptr,
        w_f1, nullptr, A1, sum+0*64, sq+0*64, nullptr, nullptr, nullptr);
    MCONV(32,32, 1,1,3,true ,false,2, 0)(A1, sum+0*64, sq+0*64, f1_g, f1_b,
        w_f2, f2_bias, FUS, nullptr, nullptr, nullptr, nullptr, nullptr);

    // guid branch: g1 (5x5 32->32, stats) -> g2 (5x5 32->8, stats) -> g3 (5x5 8->8 +bias)
    MCONV(32,32,32,2,5,false,true ,0,32)(FEAT, nullptr, nullptr, nullptr, nullptr,
        w_g1, nullptr, A1, sum+1*64, sq+1*64, nullptr, nullptr, nullptr);
    MCONV(32,32, 8,1,5,true ,true ,0, 8)(A1, sum+1*64, sq+1*64, g1_g, g1_b,
        w_g2, nullptr, A2, sum+2*64, sq+2*64, nullptr, nullptr, nullptr);
    MCONV( 8, 8, 8,1,5,true ,false,1, 8)(A2, sum+2*64, sq+2*64, g2_g, g2_b,
        w_g3, g3_bias, GUID, nullptr, nullptr, nullptr, nullptr, nullptr);

    // off_aff branch: oa1 (5x5 8->8, stats) -> oa2 (5x5 8->24, stats)
    //                 -> oa3 (5x5 24->24 +bias) fused with deform -> out
    MCONV( 8, 8, 8,1,5,false,true ,0, 8)(GUID, nullptr, nullptr, nullptr, nullptr,
        w_o1, nullptr, A2, sum+3*64, sq+3*64, nullptr, nullptr, nullptr);
    MCONV( 8, 8,24,2,5,true ,true ,0,32)(A2, sum+3*64, sq+3*64, oa1_g, oa1_b,
        w_o2, nullptr, OA2, sum+4*64, sq+4*64, nullptr, nullptr, nullptr);
    MCONV(24,32,24,2,5,true ,false,3, 0)(OA2, sum+4*64, sq+4*64, oa2_g, oa2_b,
        w_o3, oa3_bias, out, nullptr, nullptr, FUS, gk, aff_scale);
    #undef MCONV
}